// Round 7
// baseline (186.182 us; speedup 1.0000x reference)
//
#include <hip/hip_runtime.h>
#include <stdint.h>

// Problem constants
#define B_   4
#define S_   2048
#define D_   1024
#define H_   16
#define HD_  64
#define BH_  (B_*H_)      // 64
#define M_   (B_*S_)      // 8192
#define KD_  1024         // GEMM K (= D)

typedef __bf16 bf16x8 __attribute__((ext_vector_type(8)));
typedef float f32x4 __attribute__((ext_vector_type(4)));
typedef float f32x16 __attribute__((ext_vector_type(16)));
typedef unsigned int u32x4 __attribute__((ext_vector_type(4)));

__device__ __forceinline__ unsigned short f2bf(float f) {
  unsigned int u = __float_as_uint(f);
  u = u + 0x7fffu + ((u >> 16) & 1u);   // RNE
  return (unsigned short)(u >> 16);
}

__device__ __forceinline__ void gload16(const void* g, void* lds) {
  __builtin_amdgcn_global_load_lds(
      (__attribute__((address_space(1))) void*)(g),
      (__attribute__((address_space(3))) void*)(lds),
      16, 0, 0);
}

__device__ __forceinline__ bf16x8 ldfrag(const unsigned short* p) {
  return *reinterpret_cast<const bf16x8*>(p);
}

__device__ __forceinline__ unsigned int cvtpk(float lo, float hi) {
  unsigned int r;
  asm("v_cvt_pk_bf16_f32 %0, %1, %2" : "=v"(r) : "v"(lo), "v"(hi));
  return r;
}

// v_permlane32_swap_b32: a's upper 32 lanes <-> b's lower 32 lanes.
__device__ __forceinline__ void plswap(unsigned int& a, unsigned int& b) {
  asm("v_permlane32_swap_b32 %0, %1" : "+v"(a), "+v"(b));
}

__device__ __forceinline__ float2 pkadd2(float2 a, float2 b) {
  float2 r;
  asm("v_pk_add_f32 %0, %1, %2" : "=v"(r) : "v"(a), "v"(b));
  return r;
}

__device__ __forceinline__ bf16x8 mkfrag(unsigned int a, unsigned int b,
                                         unsigned int c, unsigned int d) {
  union { unsigned int w[4]; bf16x8 v; } u;
  u.w[0] = a; u.w[1] = b; u.w[2] = c; u.w[3] = d;
  return u.v;
}

// ------------- weight transpose+convert: src[R][C] f32 -> dst[C][R] bf16 -------------
__global__ __launch_bounds__(256) void wtrans(const float* __restrict__ src,
                                              unsigned short* __restrict__ dst,
                                              int R, int C) {
  __shared__ float t[32][33];
  const int c0 = blockIdx.x * 32, r0 = blockIdx.y * 32;
  const int x = threadIdx.x & 31, y = threadIdx.x >> 5;
#pragma unroll
  for (int yy = y; yy < 32; yy += 8)
    t[yy][x] = src[(size_t)(r0 + yy) * C + c0 + x];
  __syncthreads();
#pragma unroll
  for (int yy = y; yy < 32; yy += 8)
    dst[(size_t)(c0 + yy) * R + r0 + x] = f2bf(t[x][yy]);
}

// ------------- QKV GEMM with fused f32->bf16 A-conversion -------------
// A staged via reg (f32 load -> cvt_pk -> swizzled ds_write_b128, T14 split);
// B staged via global_load_lds (inverse-swizzled source). 2 LDS buffers,
// 1-deep prefetch, one barrier per K-tile (stage targets the opposite buffer,
// issued after the barrier -> race-free).
__global__ __launch_bounds__(256) void qkv_gemm(
    const float* __restrict__ Af,            // [8192][1024] f32 (x, unconverted)
    const unsigned short* __restrict__ Bt,   // [3072][1024] bf16 (w_in^T)
    const float* __restrict__ bias,          // [3072]
    unsigned short* __restrict__ Qo,         // [BH][S][64], pre-scaled
    unsigned short* __restrict__ Ko,         // [BH][S][64]
    unsigned short* __restrict__ Vto)        // [BH][64][S]  (transposed)
{
  __shared__ unsigned short Al[2][128 * 32];
  __shared__ unsigned short Bl[2][128 * 32];
  const int tid = threadIdx.x;
  const int w = tid >> 6, l = tid & 63;
  const int g = l >> 4, c = l & 15;
  const int m0 = blockIdx.y * 128, n0 = blockIdx.x * 128;
  const int wr = (w >> 1) * 64, wc = (w & 1) * 64;

  f32x4 acc[4][4] = {};

  const int srow = w * 32 + (l >> 2);          // row this thread stages
  const int lc   = l & 3;                      // logical 8-elem chunk (linear src)
  const int pch  = lc ^ ((l >> 3) & 3);        // physical chunk (XOR swizzle)
  const float* Ag0 = Af + (size_t)(m0 + srow) * KD_ + lc * 8;
  const float* Ag1 = Ag0 + (size_t)16 * KD_;
  const unsigned short* Bg = Bt + (size_t)(n0 + srow) * KD_ + pch * 8;
  // LDS element offsets for this thread's A writes (swizzled)
  const int aw0 = srow * 32 + pch * 8;
  const int aw1 = (srow + 16) * 32 + pch * 8;

  const int sA = (c >> 1) & 3;

  // helper: pack 8 f32 -> one b128 LDS write
#define APACK(dstbuf, off, v0, v1) do {                         \
    u32x4 pk_;                                                  \
    pk_[0] = cvtpk((v0).x, (v0).y); pk_[1] = cvtpk((v0).z, (v0).w); \
    pk_[2] = cvtpk((v1).x, (v1).y); pk_[3] = cvtpk((v1).z, (v1).w); \
    *reinterpret_cast<u32x4*>(&Al[dstbuf][off]) = pk_;          \
  } while (0)

  // ---- prologue: stage tile 0 ----
  {
    float4 a00 = *reinterpret_cast<const float4*>(Ag0);
    float4 a01 = *reinterpret_cast<const float4*>(Ag0 + 4);
    float4 a10 = *reinterpret_cast<const float4*>(Ag1);
    float4 a11 = *reinterpret_cast<const float4*>(Ag1 + 4);
    gload16(Bg,             &Bl[0][(w * 32) * 32]);
    gload16(Bg + 16 * KD_,  &Bl[0][(w * 32 + 16) * 32]);
    APACK(0, aw0, a00, a01);
    APACK(0, aw1, a10, a11);
  }

#pragma unroll
  for (int t = 0; t < 32; ++t) {
    const int cur = t & 1, nxt = cur ^ 1;
    asm volatile("s_waitcnt vmcnt(0) lgkmcnt(0)" ::: "memory");
    __builtin_amdgcn_s_barrier();
    __builtin_amdgcn_sched_barrier(0);

    float4 a00, a01, a10, a11;
    if (t + 1 < 32) {
      const int kt = (t + 1) * 32;
      a00 = *reinterpret_cast<const float4*>(Ag0 + kt);
      a01 = *reinterpret_cast<const float4*>(Ag0 + kt + 4);
      a10 = *reinterpret_cast<const float4*>(Ag1 + kt);
      a11 = *reinterpret_cast<const float4*>(Ag1 + kt + 4);
      gload16(Bg + kt,            &Bl[nxt][(w * 32) * 32]);
      gload16(Bg + 16 * KD_ + kt, &Bl[nxt][(w * 32 + 16) * 32]);
    }

    bf16x8 af[4], bfr[4];
#pragma unroll
    for (int i = 0; i < 4; ++i)
      af[i] = ldfrag(&Al[cur][(wr + i * 16 + c) * 32 + ((g ^ sA) << 3)]);
#pragma unroll
    for (int j = 0; j < 4; ++j)
      bfr[j] = ldfrag(&Bl[cur][(wc + j * 16 + c) * 32 + ((g ^ sA) << 3)]);
#pragma unroll
    for (int i = 0; i < 4; ++i)
#pragma unroll
      for (int j = 0; j < 4; ++j)
        acc[i][j] = __builtin_amdgcn_mfma_f32_16x16x32_bf16(af[i], bfr[j], acc[i][j], 0, 0, 0);

    if (t + 1 < 32) {
      // compiler inserts the exact vmcnt wait for a00..a11 here
      APACK(nxt, aw0, a00, a01);
      APACK(nxt, aw1, a10, a11);
    }
  }
#undef APACK

  if (n0 >= 2048) {
    // V: write directly transposed (4 consecutive tokens -> one 8B packed store).
#pragma unroll
    for (int i = 0; i < 4; ++i)
#pragma unroll
      for (int j = 0; j < 4; ++j) {
        const int ng = n0 + wc + j * 16 + c;
        const int n  = ng - 2048;
        const int hh = n >> 6, dim = n & 63;
        const int m  = m0 + wr + i * 16 + g * 4;
        const int bb = m >> 11, ss = m & 2047;
        const float bv = bias[ng];
        uint2 pk;
        pk.x = cvtpk(acc[i][j][0] + bv, acc[i][j][1] + bv);
        pk.y = cvtpk(acc[i][j][2] + bv, acc[i][j][3] + bv);
        *reinterpret_cast<uint2*>(
            &Vto[((size_t)(bb * H_ + hh) * HD_ + dim) * S_ + ss]) = pk;
      }
  } else {
#pragma unroll
    for (int i = 0; i < 4; ++i)
#pragma unroll
      for (int j = 0; j < 4; ++j)
#pragma unroll
        for (int r = 0; r < 4; ++r) {
          const int m = m0 + wr + i * 16 + g * 4 + r;
          const int n = n0 + wc + j * 16 + c;
          float v = acc[i][j][r] + bias[n];
          const int which = n >> 10;
          const int dp = n & 1023;
          const int hh = dp >> 6, dim = dp & 63;
          const int bb = m >> 11, ss = m & 2047;
          const size_t idx = ((size_t)(bb * H_ + hh) * S_ + ss) * HD_ + dim;
          // Q scale: 1/sqrt(hd) * log2(e)  (softmax runs in exp2 domain)
          if (which == 0) Qo[idx] = f2bf(v * 0.18033688f);
          else            Ko[idx] = f2bf(v);
        }
  }
}

// ------------- out GEMM (round-4 2-buffer structure, measured best) -------------
__global__ __launch_bounds__(256) void out_gemm(
    const unsigned short* __restrict__ A,
    const unsigned short* __restrict__ Bt,
    const float* __restrict__ bias,
    float* __restrict__ C)
{
  __shared__ unsigned short Al[2][128 * 32];
  __shared__ unsigned short Bl[2][128 * 32];
  const int tid = threadIdx.x;
  const int w = tid >> 6, l = tid & 63;
  const int g = l >> 4, c = l & 15;
  const int m0 = blockIdx.y * 128, n0 = blockIdx.x * 128;
  const int wr = (w >> 1) * 64, wc = (w & 1) * 64;

  f32x4 acc[4][4] = {};

  const int srow = w * 32 + (l >> 2);
  const int slc  = ((l & 3) ^ ((l >> 3) & 3)) * 8;
  const unsigned short* Ag = A  + (size_t)(m0 + srow) * KD_ + slc;
  const unsigned short* Bg = Bt + (size_t)(n0 + srow) * KD_ + slc;

  const int sA = (c >> 1) & 3;

#define GSTAGE(buf, kt) do {                                    \
    gload16(Ag + (kt),            &Al[buf][(w*32)*32]);         \
    gload16(Ag + 16*KD_ + (kt),   &Al[buf][(w*32+16)*32]);      \
    gload16(Bg + (kt),            &Bl[buf][(w*32)*32]);         \
    gload16(Bg + 16*KD_ + (kt),   &Bl[buf][(w*32+16)*32]);      \
  } while (0)

  GSTAGE(0, 0);
  int cur = 0;
  for (int kt = 0; kt < KD_; kt += 32) {
    if (kt + 32 < KD_) {
      GSTAGE(cur ^ 1, kt + 32);
      asm volatile("s_waitcnt vmcnt(4)" ::: "memory");
    } else {
      asm volatile("s_waitcnt vmcnt(0)" ::: "memory");
    }
    __builtin_amdgcn_s_barrier();
    __builtin_amdgcn_sched_barrier(0);
    bf16x8 af[4], bfr[4];
#pragma unroll
    for (int i = 0; i < 4; ++i)
      af[i] = ldfrag(&Al[cur][(wr + i * 16 + c) * 32 + ((g ^ sA) << 3)]);
#pragma unroll
    for (int j = 0; j < 4; ++j)
      bfr[j] = ldfrag(&Bl[cur][(wc + j * 16 + c) * 32 + ((g ^ sA) << 3)]);
#pragma unroll
    for (int i = 0; i < 4; ++i)
#pragma unroll
      for (int j = 0; j < 4; ++j)
        acc[i][j] = __builtin_amdgcn_mfma_f32_16x16x32_bf16(af[i], bfr[j], acc[i][j], 0, 0, 0);
    __builtin_amdgcn_sched_barrier(0);
    __builtin_amdgcn_s_barrier();
    cur ^= 1;
  }
#undef GSTAGE

#pragma unroll
  for (int i = 0; i < 4; ++i)
#pragma unroll
    for (int j = 0; j < 4; ++j)
#pragma unroll
      for (int r = 0; r < 4; ++r) {
        const int m = m0 + wr + i * 16 + g * 4 + r;
        const int n = n0 + wc + j * 16 + c;
        C[(size_t)m * D_ + n] = acc[i][j][r] + bias[n];
      }
}

// ------------- causal flash attention (round-4 2-buffer structure, measured best) -------------
__global__ __launch_bounds__(256) void attn_fwd4(
    const unsigned short* __restrict__ Q,   // [BH][S][64] (pre-scaled by 0.18033688)
    const unsigned short* __restrict__ Kg,  // [BH][S][64]
    const unsigned short* __restrict__ Vt,  // [BH][64][S]
    unsigned short* __restrict__ O)         // [B][S][1024] bf16
{
  __shared__ unsigned short Kl[2][64 * 64];
  __shared__ unsigned short Vl[2][64 * 64];

  const int tid = threadIdx.x;
  const int w = tid >> 6, l = tid & 63;
  const int q32 = l & 31, hi = l >> 5;

  // XCD-chunked swizzle: all 8 pair-blocks of one bh land on one XCD.
  const int raw = blockIdx.y * 8 + blockIdx.x;         // 0..511
  const int work = (raw & 7) * 64 + (raw >> 3);
  const int bh = work >> 3;
  const int p  = work & 7;
  const int q0A = p * 128;
  const int q0B = (15 - p) * 128;
  const int nA = 2 * (p + 1);
  const int nB = 2 * (16 - p);
  const int total = nA + nB;                           // 34 always

  const unsigned short* Kbh = Kg + (size_t)bh * (S_ * HD_);
  const unsigned short* Vbh = Vt + (size_t)bh * (HD_ * S_);

  bf16x8 qf[4];
  auto loadQ = [&](int q0) {
    const unsigned short* Qrow = Q + ((size_t)bh * S_ + q0 + w * 32 + q32) * HD_ + hi * 8;
#pragma unroll
    for (int s = 0; s < 4; ++s) qf[s] = ldfrag(Qrow + s * 16);
  };

  f32x16 od0 = {}, od1 = {};
  float lrun = 0.f;

  const int krow = w * 16 + (l >> 3);
  const int slc = ((l & 7) ^ (l >> 3)) * 8;  // inverse-swizzled source chunk

#define LDSOFF(r, ch) ((r) * 64 + (((ch) ^ ((r) & 7)) << 3))

#define STAGE(buf, tile) do {                                                   \
    const int k0s = (tile) * 64;                                                \
    gload16(Kbh + (size_t)(k0s + krow) * HD_ + slc,     &Kl[buf][(w*16)*64]);   \
    gload16(Kbh + (size_t)(k0s + krow + 8) * HD_ + slc, &Kl[buf][(w*16+8)*64]); \
    gload16(Vbh + (size_t)krow * S_ + k0s + slc,        &Vl[buf][(w*16)*64]);   \
    gload16(Vbh + (size_t)(krow + 8) * S_ + k0s + slc,  &Vl[buf][(w*16+8)*64]); \
  } while (0)

  auto epilogue = [&](int q0) {
    const float rl = 1.0f / lrun;
    const int bb = bh >> 4, hh = bh & 15;
    const int sq = q0 + w * 32 + q32;
    unsigned short* Orow = O + ((size_t)bb * S_ + sq) * D_ + hh * HD_;
#pragma unroll
    for (int rr = 0; rr < 4; ++rr) {
      uint2 v0, v1;
      v0.x = cvtpk(od0[4 * rr] * rl,     od0[4 * rr + 1] * rl);
      v0.y = cvtpk(od0[4 * rr + 2] * rl, od0[4 * rr + 3] * rl);
      *reinterpret_cast<uint2*>(Orow + 8 * rr + 4 * hi) = v0;
      v1.x = cvtpk(od1[4 * rr] * rl,     od1[4 * rr + 1] * rl);
      v1.y = cvtpk(od1[4 * rr + 2] * rl, od1[4 * rr + 3] * rl);
      *reinterpret_cast<uint2*>(Orow + 32 + 8 * rr + 4 * hi) = v1;
    }
  };

  loadQ(q0A);
  STAGE(0, 0);
  int cur = 0;
  int q0 = q0A;

  for (int idx = 0; idx < total; ++idx) {
    const bool inA = idx < nA;
    const int kv = inA ? idx : idx - nA;
    const int k0 = kv * 64;
    if (idx + 1 < total) {
      const int nkv = (idx + 1 < nA) ? idx + 1 : idx + 1 - nA;
      STAGE(cur ^ 1, nkv);
      asm volatile("s_waitcnt vmcnt(4)" ::: "memory");
    } else {
      asm volatile("s_waitcnt vmcnt(0)" ::: "memory");
    }
    __builtin_amdgcn_s_barrier();
    __builtin_amdgcn_sched_barrier(0);

    const int wqmin = q0 + w * 32;
    if (k0 <= wqmin + 31) {   // wave-tile not fully masked
      const bool live1 = (k0 + 32 <= wqmin + 31);
      const unsigned short* Kb_ = &Kl[cur][0];
      const unsigned short* Vb_ = &Vl[cur][0];

      // ---- S^T = K x Q^T ----
      f32x16 st0 = {}, st1 = {};
      __builtin_amdgcn_s_setprio(1);
#pragma unroll
      for (int s = 0; s < 4; ++s) {
        bf16x8 kf = ldfrag(Kb_ + LDSOFF(q32, 2 * s + hi));
        st0 = __builtin_amdgcn_mfma_f32_32x32x16_bf16(kf, qf[s], st0, 0, 0, 0);
      }
      if (live1) {
#pragma unroll
        for (int s = 0; s < 4; ++s) {
          bf16x8 kf = ldfrag(Kb_ + LDSOFF(32 + q32, 2 * s + hi));
          st1 = __builtin_amdgcn_mfma_f32_32x32x16_bf16(kf, qf[s], st1, 0, 0, 0);
        }
      }
      __builtin_amdgcn_s_setprio(0);

      // ---- causal mask (diagonal region only) ----
      if (k0 + 63 > wqmin) {
        const int rel = wqmin + q32 - k0;
#pragma unroll
        for (int r = 0; r < 16; ++r) {
          const int kva = (r & 3) + 8 * (r >> 2) + 4 * hi;
          if (kva > rel) st0[r] = -1e30f;
        }
        if (live1) {
#pragma unroll
          for (int r = 0; r < 16; ++r) {
            const int kva = (r & 3) + 8 * (r >> 2) + 4 * hi;
            if (kva + 32 > rel) st1[r] = -1e30f;
          }
        }
      }

      // ---- p = exp2(st) directly; row-sum via packed f32 adds ----
      float2 e0[8], e1[8];
#pragma unroll
      for (int r = 0; r < 8; ++r) {
        e0[r].x = __builtin_amdgcn_exp2f(st0[2 * r]);
        e0[r].y = __builtin_amdgcn_exp2f(st0[2 * r + 1]);
      }
      float2 a0 = pkadd2(pkadd2(e0[0], e0[1]), pkadd2(e0[2], e0[3]));
      float2 a1 = pkadd2(pkadd2(e0[4], e0[5]), pkadd2(e0[6], e0[7]));
      float2 asum = pkadd2(a0, a1);
      if (live1) {
#pragma unroll
        for (int r = 0; r < 8; ++r) {
          e1[r].x = __builtin_amdgcn_exp2f(st1[2 * r]);
          e1[r].y = __builtin_amdgcn_exp2f(st1[2 * r + 1]);
        }
        float2 b0 = pkadd2(pkadd2(e1[0], e1[1]), pkadd2(e1[2], e1[3]));
        float2 b1 = pkadd2(pkadd2(e1[4], e1[5]), pkadd2(e1[6], e1[7]));
        asum = pkadd2(asum, pkadd2(b0, b1));
      }
      float ps = asum.x + asum.y;
      ps += __shfl_xor(ps, 32);
      lrun += ps;

      // ---- P -> bf16 A-frags via cvt_pk + permlane32_swap ----
      unsigned int W0, W1, W2, W3, W4, W5, W6, W7;
      W0 = cvtpk(e0[0].x, e0[0].y); W1 = cvtpk(e0[1].x, e0[1].y);
      W2 = cvtpk(e0[2].x, e0[2].y); W3 = cvtpk(e0[3].x, e0[3].y);
      W4 = cvtpk(e0[4].x, e0[4].y); W5 = cvtpk(e0[5].x, e0[5].y);
      W6 = cvtpk(e0[6].x, e0[6].y); W7 = cvtpk(e0[7].x, e0[7].y);
      plswap(W0, W2); plswap(W1, W3); plswap(W4, W6); plswap(W5, W7);
      const bf16x8 pa0 = mkfrag(W0, W1, W2, W3);
      const bf16x8 pa1 = mkfrag(W4, W5, W6, W7);
      bf16x8 pa2, pa3;
      if (live1) {
        W0 = cvtpk(e1[0].x, e1[0].y); W1 = cvtpk(e1[1].x, e1[1].y);
        W2 = cvtpk(e1[2].x, e1[2].y); W3 = cvtpk(e1[3].x, e1[3].y);
        W4 = cvtpk(e1[4].x, e1[4].y); W5 = cvtpk(e1[5].x, e1[5].y);
        W6 = cvtpk(e1[6].x, e1[6].y); W7 = cvtpk(e1[7].x, e1[7].y);
        plswap(W0, W2); plswap(W1, W3); plswap(W4, W6); plswap(W5, W7);
        pa2 = mkfrag(W0, W1, W2, W3);
        pa3 = mkfrag(W4, W5, W6, W7);
      }

      // ---- O^T += V^T x P^T ----
      __builtin_amdgcn_s_setprio(1);
#pragma unroll
      for (int s = 0; s < 2; ++s) {
        const bf16x8 pa = (s == 0) ? pa0 : pa1;
        bf16x8 vf = ldfrag(Vb_ + LDSOFF(q32, 2 * s + hi));
        od0 = __builtin_amdgcn_mfma_f32_32x32x16_bf16(vf, pa, od0, 0, 0, 0);
        bf16x8 vg = ldfrag(Vb_ + LDSOFF(32 + q32, 2 * s + hi));
        od1 = __builtin_amdgcn_mfma_f32_32x32x16_bf16(vg, pa, od1, 0, 0, 0);
      }
      if (live1) {
#pragma unroll
        for (int s = 2; s < 4; ++s) {
          const bf16x8 pa = (s == 2) ? pa2 : pa3;
          bf16x8 vf = ldfrag(Vb_ + LDSOFF(q32, 2 * s + hi));
          od0 = __builtin_amdgcn_mfma_f32_32x32x16_bf16(vf, pa, od0, 0, 0, 0);
          bf16x8 vg = ldfrag(Vb_ + LDSOFF(32 + q32, 2 * s + hi));
          od1 = __builtin_amdgcn_mfma_f32_32x32x16_bf16(vg, pa, od1, 0, 0, 0);
        }
      }
      __builtin_amdgcn_s_setprio(0);
    }

    __builtin_amdgcn_sched_barrier(0);
    __builtin_amdgcn_s_barrier();

    // transition A -> B (register-only; no LDS hazard)
    if (idx == nA - 1) {
      epilogue(q0A);
      loadQ(q0B);
      od0 = {}; od1 = {};
      lrun = 0.f;
      q0 = q0B;
    }
    cur ^= 1;
  }

  epilogue(q0B);
#undef STAGE
#undef LDSOFF
}

extern "C" void kernel_launch(void* const* d_in, const int* in_sizes, int n_in,
                              void* d_out, int out_size, void* d_ws, size_t ws_size,
                              hipStream_t stream) {
  (void)in_sizes; (void)n_in; (void)out_size; (void)ws_size;
  const float* x     = (const float*)d_in[0];
  const float* w_in  = (const float*)d_in[1];
  const float* b_in  = (const float*)d_in[2];
  const float* w_out = (const float*)d_in[3];
  const float* b_out = (const float*)d_in[4];
  float* out = (float*)d_out;
  char* ws = (char*)d_ws;
  const size_t MB = 1024 * 1024;
  unsigned short* w_inb  = (unsigned short*)(ws);             // 6MB
  unsigned short* w_outb = (unsigned short*)(ws + 6 * MB);    // 2MB
  unsigned short* Qb     = (unsigned short*)(ws + 8 * MB);    // 16MB
  unsigned short* Kb     = (unsigned short*)(ws + 24 * MB);   // 16MB
  unsigned short* Vt     = (unsigned short*)(ws + 40 * MB);   // 16MB (transposed V)
  unsigned short* Ob     = (unsigned short*)(ws + 56 * MB);   // 16MB

  wtrans<<<dim3(96, 32), 256, 0, stream>>>(w_in, w_inb, 1024, 3072);
  wtrans<<<dim3(32, 32), 256, 0, stream>>>(w_out, w_outb, 1024, 1024);
  qkv_gemm<<<dim3(24, 64), 256, 0, stream>>>(x, w_inb, b_in, Qb, Kb, Vt);
  attn_fwd4<<<dim3(8, 64), 256, 0, stream>>>(Qb, Kb, Vt, Ob);
  out_gemm<<<dim3(8, 64), 256, 0, stream>>>(Ob, w_outb, b_out, out);
}

// Round 8
// 183.794 us; speedup vs baseline: 1.0130x; 1.0130x over previous
//
#include <hip/hip_runtime.h>
#include <stdint.h>

// Problem constants
#define B_   4
#define S_   2048
#define D_   1024
#define H_   16
#define HD_  64
#define BH_  (B_*H_)      // 64
#define M_   (B_*S_)      // 8192
#define KD_  1024         // GEMM K (= D)

typedef __bf16 bf16x8 __attribute__((ext_vector_type(8)));
typedef float f32x4 __attribute__((ext_vector_type(4)));
typedef float f32x16 __attribute__((ext_vector_type(16)));
typedef unsigned int u32x4 __attribute__((ext_vector_type(4)));

__device__ __forceinline__ unsigned short f2bf(float f) {
  unsigned int u = __float_as_uint(f);
  u = u + 0x7fffu + ((u >> 16) & 1u);   // RNE
  return (unsigned short)(u >> 16);
}

__device__ __forceinline__ void gload16(const void* g, void* lds) {
  __builtin_amdgcn_global_load_lds(
      (__attribute__((address_space(1))) void*)(g),
      (__attribute__((address_space(3))) void*)(lds),
      16, 0, 0);
}

__device__ __forceinline__ bf16x8 ldfrag(const unsigned short* p) {
  return *reinterpret_cast<const bf16x8*>(p);
}

__device__ __forceinline__ unsigned int cvtpk(float lo, float hi) {
  unsigned int r;
  asm("v_cvt_pk_bf16_f32 %0, %1, %2" : "=v"(r) : "v"(lo), "v"(hi));
  return r;
}

// v_permlane32_swap_b32: a's upper 32 lanes <-> b's lower 32 lanes.
__device__ __forceinline__ void plswap(unsigned int& a, unsigned int& b) {
  asm("v_permlane32_swap_b32 %0, %1" : "+v"(a), "+v"(b));
}

__device__ __forceinline__ float2 pkadd2(float2 a, float2 b) {
  float2 r;
  asm("v_pk_add_f32 %0, %1, %2" : "=v"(r) : "v"(a), "v"(b));
  return r;
}

__device__ __forceinline__ bf16x8 mkfrag(unsigned int a, unsigned int b,
                                         unsigned int c, unsigned int d) {
  union { unsigned int w[4]; bf16x8 v; } u;
  u.w[0] = a; u.w[1] = b; u.w[2] = c; u.w[3] = d;
  return u.v;
}

// ---------------- x: fp32 -> bf16, vectorized ----------------
__global__ __launch_bounds__(256) void xconv(const float* __restrict__ in,
                                             unsigned short* __restrict__ out) {
  const size_t i = (size_t)blockIdx.x * 256 + threadIdx.x;
  const float4* p = reinterpret_cast<const float4*>(in) + i * 2;
  float4 a = p[0], b = p[1];
  union { u32x4 v; unsigned short u[8]; } cv;
  cv.u[0] = f2bf(a.x); cv.u[1] = f2bf(a.y); cv.u[2] = f2bf(a.z); cv.u[3] = f2bf(a.w);
  cv.u[4] = f2bf(b.x); cv.u[5] = f2bf(b.y); cv.u[6] = f2bf(b.z); cv.u[7] = f2bf(b.w);
  *reinterpret_cast<u32x4*>(out + i * 8) = cv.v;
}

// ------------- weight transpose+convert: src[R][C] f32 -> dst[C][R] bf16 -------------
__global__ __launch_bounds__(256) void wtrans(const float* __restrict__ src,
                                              unsigned short* __restrict__ dst,
                                              int R, int C) {
  __shared__ float t[32][33];
  const int c0 = blockIdx.x * 32, r0 = blockIdx.y * 32;
  const int x = threadIdx.x & 31, y = threadIdx.x >> 5;
#pragma unroll
  for (int yy = y; yy < 32; yy += 8)
    t[yy][x] = src[(size_t)(r0 + yy) * C + c0 + x];
  __syncthreads();
#pragma unroll
  for (int yy = y; yy < 32; yy += 8)
    dst[(size_t)(c0 + yy) * R + r0 + x] = f2bf(t[x][yy]);
}

// ------------- QKV GEMM: 256x256 tile, BK=64, 8 waves, 4-phase schedule -------------
// Per K-tile: 4 quadrant phases, each {12 ds_read ; half-tile prefetch ; barrier ;
// lgkmcnt(0) ; setprio(1) ; 16 MFMA ; setprio(0) ; barrier}. Stages for kt+1 go
// into buf^1 during phases 0-1 (buf^1's readers finished last K-tile); single
// vmcnt(0) at phase-3 tail (~2.5 phases after issue). Row-XOR LDS swizzle
// (chunk ^= (row>>1)&7), inverse-applied on the global source (rule #21).
__global__ __launch_bounds__(512, 2) void qkv_gemm8(
    const unsigned short* __restrict__ A,    // [8192][1024] bf16 (x)
    const unsigned short* __restrict__ Bt,   // [3072][1024] bf16 (w_in^T)
    const float* __restrict__ bias,          // [3072]
    unsigned short* __restrict__ Qo,         // [BH][S][64], pre-scaled
    unsigned short* __restrict__ Ko,         // [BH][S][64]
    unsigned short* __restrict__ Vto)        // [BH][64][S]  (transposed)
{
  __shared__ unsigned short As[2][2][128 * 64];   // [kbuf][mhalf][row*64+col]
  __shared__ unsigned short Bs[2][2][128 * 64];   // [kbuf][nhalf]

  const int tid = threadIdx.x;
  const int w = tid >> 6, l = tid & 63;
  const int c = l & 15, g = l >> 4;
  const int wm = w >> 2, wn = w & 3;              // 2M x 4N wave grid
  const int m0 = blockIdx.y * 256, n0 = blockIdx.x * 256;

  f32x4 acc[8][4] = {};

  // ---- staging addressing (64-row stripe per (wave,pass)) ----
  const int srow = w * 8 + (l >> 3);              // 0..63
  const int schunk = ((l & 7) ^ ((w * 4 + (l >> 4)) & 7)) * 8;  // inverse swizzle
  const unsigned short* Asrc = A  + (size_t)(m0 + srow) * KD_ + schunk;
  const unsigned short* Bsrc = Bt + (size_t)(n0 + srow) * KD_ + schunk;
  const int ldst = (w * 8) * 64;                  // wave-uniform LDS base (elems)

#define STAGE_A(b_, kt_) do {                                              \
    gload16(Asrc + (kt_) * 64,                     &As[b_][0][ldst]);      \
    gload16(Asrc + (size_t)64  * KD_ + (kt_) * 64, &As[b_][0][ldst + 4096]); \
    gload16(Asrc + (size_t)128 * KD_ + (kt_) * 64, &As[b_][1][ldst]);      \
    gload16(Asrc + (size_t)192 * KD_ + (kt_) * 64, &As[b_][1][ldst + 4096]); \
  } while (0)
#define STAGE_B(b_, kt_) do {                                              \
    gload16(Bsrc + (kt_) * 64,                     &Bs[b_][0][ldst]);      \
    gload16(Bsrc + (size_t)64  * KD_ + (kt_) * 64, &Bs[b_][0][ldst + 4096]); \
    gload16(Bsrc + (size_t)128 * KD_ + (kt_) * 64, &Bs[b_][1][ldst]);      \
    gload16(Bsrc + (size_t)192 * KD_ + (kt_) * 64, &Bs[b_][1][ldst + 4096]); \
  } while (0)

  const int sw = c >> 1;                          // read-side swizzle selector

#define PHASE(BUF_, QM_, QN_, STAGING_, TAILWAIT_)                          \
  {                                                                         \
    bf16x8 af[4][2], bfr[2][2];                                             \
    _Pragma("unroll")                                                       \
    for (int i_ = 0; i_ < 4; ++i_) {                                        \
      const int rA = (QM_) * 64 + i_ * 16 + c;                              \
      _Pragma("unroll")                                                     \
      for (int ks = 0; ks < 2; ++ks)                                        \
        af[i_][ks] = ldfrag(&As[BUF_][wm][rA * 64 + (((ks << 2) + g) ^ sw) * 8]); \
    }                                                                       \
    _Pragma("unroll")                                                       \
    for (int j_ = 0; j_ < 2; ++j_) {                                        \
      const int rB = (wn & 1) * 64 + (QN_) * 32 + j_ * 16 + c;              \
      _Pragma("unroll")                                                     \
      for (int ks = 0; ks < 2; ++ks)                                        \
        bfr[j_][ks] = ldfrag(&Bs[BUF_][wn >> 1][rB * 64 + (((ks << 2) + g) ^ sw) * 8]); \
    }                                                                       \
    STAGING_                                                                \
    __builtin_amdgcn_s_barrier();                                           \
    asm volatile("s_waitcnt lgkmcnt(0)" ::: "memory");                      \
    __builtin_amdgcn_sched_barrier(0);                                      \
    __builtin_amdgcn_s_setprio(1);                                          \
    _Pragma("unroll")                                                       \
    for (int i_ = 0; i_ < 4; ++i_)                                          \
      _Pragma("unroll")                                                     \
      for (int j_ = 0; j_ < 2; ++j_)                                        \
        _Pragma("unroll")                                                   \
        for (int ks = 0; ks < 2; ++ks)                                      \
          acc[(QM_) * 4 + i_][(QN_) * 2 + j_] =                             \
              __builtin_amdgcn_mfma_f32_16x16x32_bf16(                      \
                  af[i_][ks], bfr[j_][ks],                                  \
                  acc[(QM_) * 4 + i_][(QN_) * 2 + j_], 0, 0, 0);            \
    __builtin_amdgcn_s_setprio(0);                                          \
    TAILWAIT_                                                               \
    __builtin_amdgcn_s_barrier();                                           \
  }

  // ---- prologue: stage kt=0 into buf0 ----
  STAGE_A(0, 0);
  STAGE_B(0, 0);
  asm volatile("s_waitcnt vmcnt(0)" ::: "memory");
  __builtin_amdgcn_s_barrier();

  for (int kt = 0; kt < 16; ++kt) {
    const int buf = kt & 1;
    if (kt < 15) {
      PHASE(buf, 0, 0, STAGE_A(buf ^ 1, kt + 1);, )
      PHASE(buf, 1, 0, STAGE_B(buf ^ 1, kt + 1);, )
    } else {
      PHASE(buf, 0, 0, , )
      PHASE(buf, 1, 0, , )
    }
    PHASE(buf, 0, 1, , )
    PHASE(buf, 1, 1, , asm volatile("s_waitcnt vmcnt(0)" ::: "memory");)
  }
#undef PHASE
#undef STAGE_A
#undef STAGE_B

  // ---- epilogue ----
  if (n0 >= 2048) {
    // V: direct-transposed (4 consecutive tokens -> one 8B packed store)
#pragma unroll
    for (int mi = 0; mi < 8; ++mi)
#pragma unroll
      for (int nj = 0; nj < 4; ++nj) {
        const int ng = n0 + wn * 64 + nj * 16 + c;
        const int nn = ng - 2048;
        const int hh = nn >> 6, dim = nn & 63;
        const int m  = m0 + wm * 128 + mi * 16 + g * 4;
        const int bb = m >> 11, ss = m & 2047;
        const float bv = bias[ng];
        uint2 pk;
        pk.x = cvtpk(acc[mi][nj][0] + bv, acc[mi][nj][1] + bv);
        pk.y = cvtpk(acc[mi][nj][2] + bv, acc[mi][nj][3] + bv);
        *reinterpret_cast<uint2*>(
            &Vto[((size_t)(bb * H_ + hh) * HD_ + dim) * S_ + ss]) = pk;
      }
  } else {
#pragma unroll
    for (int mi = 0; mi < 8; ++mi)
#pragma unroll
      for (int nj = 0; nj < 4; ++nj)
#pragma unroll
        for (int r = 0; r < 4; ++r) {
          const int m = m0 + wm * 128 + mi * 16 + g * 4 + r;
          const int n = n0 + wn * 64 + nj * 16 + c;
          float v = acc[mi][nj][r] + bias[n];
          const int which = n >> 10;                  // uniform per block
          const int dp = n & 1023;
          const int hh = dp >> 6, dim = dp & 63;
          const int bb = m >> 11, ss = m & 2047;
          const size_t idx = ((size_t)(bb * H_ + hh) * S_ + ss) * HD_ + dim;
          // Q scale: 1/sqrt(hd) * log2(e)  (softmax runs in exp2 domain)
          if (which == 0) Qo[idx] = f2bf(v * 0.18033688f);
          else            Ko[idx] = f2bf(v);
        }
  }
}

// ------------- out GEMM (round-4 2-buffer structure, measured best) -------------
__global__ __launch_bounds__(256) void out_gemm(
    const unsigned short* __restrict__ A,
    const unsigned short* __restrict__ Bt,
    const float* __restrict__ bias,
    float* __restrict__ C)
{
  __shared__ unsigned short Al[2][128 * 32];
  __shared__ unsigned short Bl[2][128 * 32];
  const int tid = threadIdx.x;
  const int w = tid >> 6, l = tid & 63;
  const int g = l >> 4, c = l & 15;
  const int m0 = blockIdx.y * 128, n0 = blockIdx.x * 128;
  const int wr = (w >> 1) * 64, wc = (w & 1) * 64;

  f32x4 acc[4][4] = {};

  const int srow = w * 32 + (l >> 2);
  const int slc  = ((l & 3) ^ ((l >> 3) & 3)) * 8;
  const unsigned short* Ag = A  + (size_t)(m0 + srow) * KD_ + slc;
  const unsigned short* Bg = Bt + (size_t)(n0 + srow) * KD_ + slc;

  const int sA = (c >> 1) & 3;

#define GSTAGE(buf, kt) do {                                    \
    gload16(Ag + (kt),            &Al[buf][(w*32)*32]);         \
    gload16(Ag + 16*KD_ + (kt),   &Al[buf][(w*32+16)*32]);      \
    gload16(Bg + (kt),            &Bl[buf][(w*32)*32]);         \
    gload16(Bg + 16*KD_ + (kt),   &Bl[buf][(w*32+16)*32]);      \
  } while (0)

  GSTAGE(0, 0);
  int cur = 0;
  for (int kt = 0; kt < KD_; kt += 32) {
    if (kt + 32 < KD_) {
      GSTAGE(cur ^ 1, kt + 32);
      asm volatile("s_waitcnt vmcnt(4)" ::: "memory");
    } else {
      asm volatile("s_waitcnt vmcnt(0)" ::: "memory");
    }
    __builtin_amdgcn_s_barrier();
    __builtin_amdgcn_sched_barrier(0);
    bf16x8 af[4], bfr[4];
#pragma unroll
    for (int i = 0; i < 4; ++i)
      af[i] = ldfrag(&Al[cur][(wr + i * 16 + c) * 32 + ((g ^ sA) << 3)]);
#pragma unroll
    for (int j = 0; j < 4; ++j)
      bfr[j] = ldfrag(&Bl[cur][(wc + j * 16 + c) * 32 + ((g ^ sA) << 3)]);
#pragma unroll
    for (int i = 0; i < 4; ++i)
#pragma unroll
      for (int j = 0; j < 4; ++j)
        acc[i][j] = __builtin_amdgcn_mfma_f32_16x16x32_bf16(af[i], bfr[j], acc[i][j], 0, 0, 0);
    __builtin_amdgcn_sched_barrier(0);
    __builtin_amdgcn_s_barrier();
    cur ^= 1;
  }
#undef GSTAGE

#pragma unroll
  for (int i = 0; i < 4; ++i)
#pragma unroll
    for (int j = 0; j < 4; ++j)
#pragma unroll
      for (int r = 0; r < 4; ++r) {
        const int m = m0 + wr + i * 16 + g * 4 + r;
        const int n = n0 + wc + j * 16 + c;
        C[(size_t)m * D_ + n] = acc[i][j][r] + bias[n];
      }
}

// ------------- causal flash attention (round-4 2-buffer structure, measured best) -------------
__global__ __launch_bounds__(256) void attn_fwd4(
    const unsigned short* __restrict__ Q,   // [BH][S][64] (pre-scaled by 0.18033688)
    const unsigned short* __restrict__ Kg,  // [BH][S][64]
    const unsigned short* __restrict__ Vt,  // [BH][64][S]
    unsigned short* __restrict__ O)         // [B][S][1024] bf16
{
  __shared__ unsigned short Kl[2][64 * 64];
  __shared__ unsigned short Vl[2][64 * 64];

  const int tid = threadIdx.x;
  const int w = tid >> 6, l = tid & 63;
  const int q32 = l & 31, hi = l >> 5;

  // XCD-chunked swizzle: all 8 pair-blocks of one bh land on one XCD.
  const int raw = blockIdx.y * 8 + blockIdx.x;         // 0..511
  const int work = (raw & 7) * 64 + (raw >> 3);
  const int bh = work >> 3;
  const int p  = work & 7;
  const int q0A = p * 128;
  const int q0B = (15 - p) * 128;
  const int nA = 2 * (p + 1);
  const int nB = 2 * (16 - p);
  const int total = nA + nB;                           // 34 always

  const unsigned short* Kbh = Kg + (size_t)bh * (S_ * HD_);
  const unsigned short* Vbh = Vt + (size_t)bh * (HD_ * S_);

  bf16x8 qf[4];
  auto loadQ = [&](int q0) {
    const unsigned short* Qrow = Q + ((size_t)bh * S_ + q0 + w * 32 + q32) * HD_ + hi * 8;
#pragma unroll
    for (int s = 0; s < 4; ++s) qf[s] = ldfrag(Qrow + s * 16);
  };

  f32x16 od0 = {}, od1 = {};
  float lrun = 0.f;

  const int krow = w * 16 + (l >> 3);
  const int slc = ((l & 7) ^ (l >> 3)) * 8;  // inverse-swizzled source chunk

#define LDSOFF(r, ch) ((r) * 64 + (((ch) ^ ((r) & 7)) << 3))

#define STAGE(buf, tile) do {                                                   \
    const int k0s = (tile) * 64;                                                \
    gload16(Kbh + (size_t)(k0s + krow) * HD_ + slc,     &Kl[buf][(w*16)*64]);   \
    gload16(Kbh + (size_t)(k0s + krow + 8) * HD_ + slc, &Kl[buf][(w*16+8)*64]); \
    gload16(Vbh + (size_t)krow * S_ + k0s + slc,        &Vl[buf][(w*16)*64]);   \
    gload16(Vbh + (size_t)(krow + 8) * S_ + k0s + slc,  &Vl[buf][(w*16+8)*64]); \
  } while (0)

  auto epilogue = [&](int q0) {
    const float rl = 1.0f / lrun;
    const int bb = bh >> 4, hh = bh & 15;
    const int sq = q0 + w * 32 + q32;
    unsigned short* Orow = O + ((size_t)bb * S_ + sq) * D_ + hh * HD_;
#pragma unroll
    for (int rr = 0; rr < 4; ++rr) {
      uint2 v0, v1;
      v0.x = cvtpk(od0[4 * rr] * rl,     od0[4 * rr + 1] * rl);
      v0.y = cvtpk(od0[4 * rr + 2] * rl, od0[4 * rr + 3] * rl);
      *reinterpret_cast<uint2*>(Orow + 8 * rr + 4 * hi) = v0;
      v1.x = cvtpk(od1[4 * rr] * rl,     od1[4 * rr + 1] * rl);
      v1.y = cvtpk(od1[4 * rr + 2] * rl, od1[4 * rr + 3] * rl);
      *reinterpret_cast<uint2*>(Orow + 32 + 8 * rr + 4 * hi) = v1;
    }
  };

  loadQ(q0A);
  STAGE(0, 0);
  int cur = 0;
  int q0 = q0A;

  for (int idx = 0; idx < total; ++idx) {
    const bool inA = idx < nA;
    const int kv = inA ? idx : idx - nA;
    const int k0 = kv * 64;
    if (idx + 1 < total) {
      const int nkv = (idx + 1 < nA) ? idx + 1 : idx + 1 - nA;
      STAGE(cur ^ 1, nkv);
      asm volatile("s_waitcnt vmcnt(4)" ::: "memory");
    } else {
      asm volatile("s_waitcnt vmcnt(0)" ::: "memory");
    }
    __builtin_amdgcn_s_barrier();
    __builtin_amdgcn_sched_barrier(0);

    const int wqmin = q0 + w * 32;
    if (k0 <= wqmin + 31) {   // wave-tile not fully masked
      const bool live1 = (k0 + 32 <= wqmin + 31);
      const unsigned short* Kb_ = &Kl[cur][0];
      const unsigned short* Vb_ = &Vl[cur][0];

      // ---- S^T = K x Q^T ----
      f32x16 st0 = {}, st1 = {};
      __builtin_amdgcn_s_setprio(1);
#pragma unroll
      for (int s = 0; s < 4; ++s) {
        bf16x8 kf = ldfrag(Kb_ + LDSOFF(q32, 2 * s + hi));
        st0 = __builtin_amdgcn_mfma_f32_32x32x16_bf16(kf, qf[s], st0, 0, 0, 0);
      }
      if (live1) {
#pragma unroll
        for (int s = 0; s < 4; ++s) {
          bf16x8 kf = ldfrag(Kb_ + LDSOFF(32 + q32, 2 * s + hi));
          st1 = __builtin_amdgcn_mfma_f32_32x32x16_bf16(kf, qf[s], st1, 0, 0, 0);
        }
      }
      __builtin_amdgcn_s_setprio(0);

      // ---- causal mask (diagonal region only) ----
      if (k0 + 63 > wqmin) {
        const int rel = wqmin + q32 - k0;
#pragma unroll
        for (int r = 0; r < 16; ++r) {
          const int kva = (r & 3) + 8 * (r >> 2) + 4 * hi;
          if (kva > rel) st0[r] = -1e30f;
        }
        if (live1) {
#pragma unroll
          for (int r = 0; r < 16; ++r) {
            const int kva = (r & 3) + 8 * (r >> 2) + 4 * hi;
            if (kva + 32 > rel) st1[r] = -1e30f;
          }
        }
      }

      // ---- p = exp2(st) directly; row-sum via packed f32 adds ----
      float2 e0[8], e1[8];
#pragma unroll
      for (int r = 0; r < 8; ++r) {
        e0[r].x = __builtin_amdgcn_exp2f(st0[2 * r]);
        e0[r].y = __builtin_amdgcn_exp2f(st0[2 * r + 1]);
      }
      float2 a0 = pkadd2(pkadd2(e0[0], e0[1]), pkadd2(e0[2], e0[3]));
      float2 a1 = pkadd2(pkadd2(e0[4], e0[5]), pkadd2(e0[6], e0[7]));
      float2 asum = pkadd2(a0, a1);
      if (live1) {
#pragma unroll
        for (int r = 0; r < 8; ++r) {
          e1[r].x = __builtin_amdgcn_exp2f(st1[2 * r]);
          e1[r].y = __builtin_amdgcn_exp2f(st1[2 * r + 1]);
        }
        float2 b0 = pkadd2(pkadd2(e1[0], e1[1]), pkadd2(e1[2], e1[3]));
        float2 b1 = pkadd2(pkadd2(e1[4], e1[5]), pkadd2(e1[6], e1[7]));
        asum = pkadd2(asum, pkadd2(b0, b1));
      }
      float ps = asum.x + asum.y;
      ps += __shfl_xor(ps, 32);
      lrun += ps;

      // ---- P -> bf16 A-frags via cvt_pk + permlane32_swap ----
      unsigned int W0, W1, W2, W3, W4, W5, W6, W7;
      W0 = cvtpk(e0[0].x, e0[0].y); W1 = cvtpk(e0[1].x, e0[1].y);
      W2 = cvtpk(e0[2].x, e0[2].y); W3 = cvtpk(e0[3].x, e0[3].y);
      W4 = cvtpk(e0[4].x, e0[4].y); W5 = cvtpk(e0[5].x, e0[5].y);
      W6 = cvtpk(e0[6].x, e0[6].y); W7 = cvtpk(e0[7].x, e0[7].y);
      plswap(W0, W2); plswap(W1, W3); plswap(W4, W6); plswap(W5, W7);
      const bf16x8 pa0 = mkfrag(W0, W1, W2, W3);
      const bf16x8 pa1 = mkfrag(W4, W5, W6, W7);
      bf16x8 pa2, pa3;
      if (live1) {
        W0 = cvtpk(e1[0].x, e1[0].y); W1 = cvtpk(e1[1].x, e1[1].y);
        W2 = cvtpk(e1[2].x, e1[2].y); W3 = cvtpk(e1[3].x, e1[3].y);
        W4 = cvtpk(e1[4].x, e1[4].y); W5 = cvtpk(e1[5].x, e1[5].y);
        W6 = cvtpk(e1[6].x, e1[6].y); W7 = cvtpk(e1[7].x, e1[7].y);
        plswap(W0, W2); plswap(W1, W3); plswap(W4, W6); plswap(W5, W7);
        pa2 = mkfrag(W0, W1, W2, W3);
        pa3 = mkfrag(W4, W5, W6, W7);
      }

      // ---- O^T += V^T x P^T ----
      __builtin_amdgcn_s_setprio(1);
#pragma unroll
      for (int s = 0; s < 2; ++s) {
        const bf16x8 pa = (s == 0) ? pa0 : pa1;
        bf16x8 vf = ldfrag(Vb_ + LDSOFF(q32, 2 * s + hi));
        od0 = __builtin_amdgcn_mfma_f32_32x32x16_bf16(vf, pa, od0, 0, 0, 0);
        bf16x8 vg = ldfrag(Vb_ + LDSOFF(32 + q32, 2 * s + hi));
        od1 = __builtin_amdgcn_mfma_f32_32x32x16_bf16(vg, pa, od1, 0, 0, 0);
      }
      if (live1) {
#pragma unroll
        for (int s = 2; s < 4; ++s) {
          const bf16x8 pa = (s == 2) ? pa2 : pa3;
          bf16x8 vf = ldfrag(Vb_ + LDSOFF(q32, 2 * s + hi));
          od0 = __builtin_amdgcn_mfma_f32_32x32x16_bf16(vf, pa, od0, 0, 0, 0);
          bf16x8 vg = ldfrag(Vb_ + LDSOFF(32 + q32, 2 * s + hi));
          od1 = __builtin_amdgcn_mfma_f32_32x32x16_bf16(vg, pa, od1, 0, 0, 0);
        }
      }
      __builtin_amdgcn_s_setprio(0);
    }

    __builtin_amdgcn_sched_barrier(0);
    __builtin_amdgcn_s_barrier();

    // transition A -> B (register-only; no LDS hazard)
    if (idx == nA - 1) {
      epilogue(q0A);
      loadQ(q0B);
      od0 = {}; od1 = {};
      lrun = 0.f;
      q0 = q0B;
    }
    cur ^= 1;
  }

  epilogue(q0B);
#undef STAGE
#undef LDSOFF
}

extern "C" void kernel_launch(void* const* d_in, const int* in_sizes, int n_in,
                              void* d_out, int out_size, void* d_ws, size_t ws_size,
                              hipStream_t stream) {
  (void)in_sizes; (void)n_in; (void)out_size; (void)ws_size;
  const float* x     = (const float*)d_in[0];
  const float* w_in  = (const float*)d_in[1];
  const float* b_in  = (const float*)d_in[2];
  const float* w_out = (const float*)d_in[3];
  const float* b_out = (const float*)d_in[4];
  float* out = (float*)d_out;
  char* ws = (char*)d_ws;
  const size_t MB = 1024 * 1024;
  unsigned short* xb     = (unsigned short*)(ws);             // 16MB
  unsigned short* w_inb  = (unsigned short*)(ws + 16 * MB);   // 6MB
  unsigned short* w_outb = (unsigned short*)(ws + 22 * MB);   // 2MB
  unsigned short* Qb     = (unsigned short*)(ws + 24 * MB);   // 16MB
  unsigned short* Kb     = (unsigned short*)(ws + 40 * MB);   // 16MB
  unsigned short* Vt     = (unsigned short*)(ws + 56 * MB);   // 16MB (transposed V)
  unsigned short* Ob     = (unsigned short*)(ws + 72 * MB);   // 16MB

  xconv<<<4096, 256, 0, stream>>>(x, xb);
  wtrans<<<dim3(96, 32), 256, 0, stream>>>(w_in, w_inb, 1024, 3072);
  wtrans<<<dim3(32, 32), 256, 0, stream>>>(w_out, w_outb, 1024, 1024);
  qkv_gemm8<<<dim3(12, 32), 512, 0, stream>>>(xb, w_inb, b_in, Qb, Kb, Vt);
  attn_fwd4<<<dim3(8, 64), 256, 0, stream>>>(Qb, Kb, Vt, Ob);
  out_gemm<<<dim3(8, 64), 256, 0, stream>>>(Ob, w_outb, b_out, out);
}

// Round 9
// 175.296 us; speedup vs baseline: 1.0621x; 1.0485x over previous
//
#include <hip/hip_runtime.h>
#include <stdint.h>

// Problem constants
#define B_   4
#define S_   2048
#define D_   1024
#define H_   16
#define HD_  64
#define BH_  (B_*H_)      // 64
#define M_   (B_*S_)      // 8192
#define KD_  1024         // GEMM K (= D)

typedef __bf16 bf16x8 __attribute__((ext_vector_type(8)));
typedef float f32x4 __attribute__((ext_vector_type(4)));
typedef float f32x16 __attribute__((ext_vector_type(16)));
typedef unsigned int u32x4 __attribute__((ext_vector_type(4)));

__device__ __forceinline__ unsigned short f2bf(float f) {
  unsigned int u = __float_as_uint(f);
  u = u + 0x7fffu + ((u >> 16) & 1u);   // RNE
  return (unsigned short)(u >> 16);
}

__device__ __forceinline__ void gload16(const void* g, void* lds) {
  __builtin_amdgcn_global_load_lds(
      (__attribute__((address_space(1))) void*)(g),
      (__attribute__((address_space(3))) void*)(lds),
      16, 0, 0);
}

__device__ __forceinline__ bf16x8 ldfrag(const unsigned short* p) {
  return *reinterpret_cast<const bf16x8*>(p);
}

__device__ __forceinline__ unsigned int cvtpk(float lo, float hi) {
  unsigned int r;
  asm("v_cvt_pk_bf16_f32 %0, %1, %2" : "=v"(r) : "v"(lo), "v"(hi));
  return r;
}

// v_permlane32_swap_b32: a's upper 32 lanes <-> b's lower 32 lanes.
__device__ __forceinline__ void plswap(unsigned int& a, unsigned int& b) {
  asm("v_permlane32_swap_b32 %0, %1" : "+v"(a), "+v"(b));
}

__device__ __forceinline__ float2 pkadd2(float2 a, float2 b) {
  float2 r;
  asm("v_pk_add_f32 %0, %1, %2" : "=v"(r) : "v"(a), "v"(b));
  return r;
}

__device__ __forceinline__ bf16x8 mkfrag(unsigned int a, unsigned int b,
                                         unsigned int c, unsigned int d) {
  union { unsigned int w[4]; bf16x8 v; } u;
  u.w[0] = a; u.w[1] = b; u.w[2] = c; u.w[3] = d;
  return u.v;
}

// ------------- fused prep: x f32->bf16 copy + both weight transposes -------------
// blocks [0,4096): xconv; [4096,7168): w_in^T; [7168,8192): w_out^T.
__global__ __launch_bounds__(256) void prep(
    const float* __restrict__ x,     unsigned short* __restrict__ xb,
    const float* __restrict__ w_in,  unsigned short* __restrict__ w_inb,
    const float* __restrict__ w_out, unsigned short* __restrict__ w_outb) {
  const int bid = blockIdx.x;
  const int tid = threadIdx.x;
  if (bid < 4096) {
    const size_t i = (size_t)bid * 256 + tid;
    const float4* p = reinterpret_cast<const float4*>(x) + i * 2;
    float4 a = p[0], b = p[1];
    union { u32x4 v; unsigned short u[8]; } cv;
    cv.u[0] = f2bf(a.x); cv.u[1] = f2bf(a.y); cv.u[2] = f2bf(a.z); cv.u[3] = f2bf(a.w);
    cv.u[4] = f2bf(b.x); cv.u[5] = f2bf(b.y); cv.u[6] = f2bf(b.z); cv.u[7] = f2bf(b.w);
    *reinterpret_cast<u32x4*>(xb + i * 8) = cv.v;
    return;
  }
  __shared__ float t[32][33];
  const float* src; unsigned short* dst; int R, C, c0, r0;
  if (bid < 7168) {
    const int b = bid - 4096;                 // w_in: R=1024, C=3072, grid 96x32
    src = w_in; dst = w_inb; R = 1024; C = 3072;
    c0 = (b % 96) * 32; r0 = (b / 96) * 32;
  } else {
    const int b = bid - 7168;                 // w_out: R=1024, C=1024, grid 32x32
    src = w_out; dst = w_outb; R = 1024; C = 1024;
    c0 = (b % 32) * 32; r0 = (b / 32) * 32;
  }
  const int xx = tid & 31, yy = tid >> 5;
#pragma unroll
  for (int y2 = yy; y2 < 32; y2 += 8)
    t[y2][xx] = src[(size_t)(r0 + y2) * C + c0 + xx];
  __syncthreads();
#pragma unroll
  for (int y2 = yy; y2 < 32; y2 += 8)
    dst[(size_t)(c0 + y2) * R + r0 + xx] = f2bf(t[xx][y2]);
}

// ------------- QKV GEMM (round-4 measured-best structure + XCD n-chunk swizzle) -------------
// 128x128 tile, BK=32, 2 LDS buffers, 1-deep prefetch, counted vmcnt(4).
// Grid flat 1536; xcd = bid&7 owns n-blocks [3*xcd, 3*xcd+3) (768KB B-panel,
// L2-resident per XCD); m streams within.
__global__ __launch_bounds__(256) void qkv_gemm(
    const unsigned short* __restrict__ A,    // [8192][1024] bf16 (x)
    const unsigned short* __restrict__ Bt,   // [3072][1024] bf16 (w_in^T)
    const float* __restrict__ bias,          // [3072]
    unsigned short* __restrict__ Qo,         // [BH][S][64], pre-scaled
    unsigned short* __restrict__ Ko,         // [BH][S][64]
    unsigned short* __restrict__ Vto)        // [BH][64][S]  (transposed)
{
  __shared__ unsigned short Al[2][128 * 32];
  __shared__ unsigned short Bl[2][128 * 32];
  const int tid = threadIdx.x;
  const int w = tid >> 6, l = tid & 63;
  const int g = l >> 4, c = l & 15;
  const int flat = blockIdx.x;
  const int xcd = flat & 7, rr_ = flat >> 3;       // 0..191
  const int n0 = (xcd * 3 + (rr_ >> 6)) * 128;     // n-chunk per XCD
  const int m0 = (rr_ & 63) * 128;
  const int wr = (w >> 1) * 64, wc = (w & 1) * 64;

  f32x4 acc[4][4] = {};

  const int srow = w * 32 + (l >> 2);
  const int slc  = ((l & 3) ^ ((l >> 3) & 3)) * 8;
  const unsigned short* Ag = A  + (size_t)(m0 + srow) * KD_ + slc;
  const unsigned short* Bg = Bt + (size_t)(n0 + srow) * KD_ + slc;

  const int sA = (c >> 1) & 3;

#define GSTAGE(buf, kt) do {                                    \
    gload16(Ag + (kt),            &Al[buf][(w*32)*32]);         \
    gload16(Ag + 16*KD_ + (kt),   &Al[buf][(w*32+16)*32]);      \
    gload16(Bg + (kt),            &Bl[buf][(w*32)*32]);         \
    gload16(Bg + 16*KD_ + (kt),   &Bl[buf][(w*32+16)*32]);      \
  } while (0)

  GSTAGE(0, 0);
  int cur = 0;
  for (int kt = 0; kt < KD_; kt += 32) {
    if (kt + 32 < KD_) {
      GSTAGE(cur ^ 1, kt + 32);
      asm volatile("s_waitcnt vmcnt(4)" ::: "memory");
    } else {
      asm volatile("s_waitcnt vmcnt(0)" ::: "memory");
    }
    __builtin_amdgcn_s_barrier();
    __builtin_amdgcn_sched_barrier(0);
    bf16x8 af[4], bfr[4];
#pragma unroll
    for (int i = 0; i < 4; ++i)
      af[i] = ldfrag(&Al[cur][(wr + i * 16 + c) * 32 + ((g ^ sA) << 3)]);
#pragma unroll
    for (int j = 0; j < 4; ++j)
      bfr[j] = ldfrag(&Bl[cur][(wc + j * 16 + c) * 32 + ((g ^ sA) << 3)]);
#pragma unroll
    for (int i = 0; i < 4; ++i)
#pragma unroll
      for (int j = 0; j < 4; ++j)
        acc[i][j] = __builtin_amdgcn_mfma_f32_16x16x32_bf16(af[i], bfr[j], acc[i][j], 0, 0, 0);
    __builtin_amdgcn_sched_barrier(0);
    __builtin_amdgcn_s_barrier();
    cur ^= 1;
  }
#undef GSTAGE

  if (n0 >= 2048) {
    // V: write directly transposed (4 consecutive tokens -> one 8B packed store).
#pragma unroll
    for (int i = 0; i < 4; ++i)
#pragma unroll
      for (int j = 0; j < 4; ++j) {
        const int ng = n0 + wc + j * 16 + c;
        const int n  = ng - 2048;
        const int hh = n >> 6, dim = n & 63;
        const int m  = m0 + wr + i * 16 + g * 4;
        const int bb = m >> 11, ss = m & 2047;
        const float bv = bias[ng];
        uint2 pk;
        pk.x = cvtpk(acc[i][j][0] + bv, acc[i][j][1] + bv);
        pk.y = cvtpk(acc[i][j][2] + bv, acc[i][j][3] + bv);
        *reinterpret_cast<uint2*>(
            &Vto[((size_t)(bb * H_ + hh) * HD_ + dim) * S_ + ss]) = pk;
      }
  } else {
#pragma unroll
    for (int i = 0; i < 4; ++i)
#pragma unroll
      for (int j = 0; j < 4; ++j)
#pragma unroll
        for (int r = 0; r < 4; ++r) {
          const int m = m0 + wr + i * 16 + g * 4 + r;
          const int n = n0 + wc + j * 16 + c;
          float v = acc[i][j][r] + bias[n];
          const int which = n >> 10;
          const int dp = n & 1023;
          const int hh = dp >> 6, dim = dp & 63;
          const int bb = m >> 11, ss = m & 2047;
          const size_t idx = ((size_t)(bb * H_ + hh) * S_ + ss) * HD_ + dim;
          // Q scale: 1/sqrt(hd) * log2(e)  (softmax runs in exp2 domain)
          if (which == 0) Qo[idx] = f2bf(v * 0.18033688f);
          else            Ko[idx] = f2bf(v);
        }
  }
}

// ------------- out GEMM (round-4 structure + XCD n-chunk swizzle) -------------
__global__ __launch_bounds__(256) void out_gemm(
    const unsigned short* __restrict__ A,
    const unsigned short* __restrict__ Bt,
    const float* __restrict__ bias,
    float* __restrict__ C)
{
  __shared__ unsigned short Al[2][128 * 32];
  __shared__ unsigned short Bl[2][128 * 32];
  const int tid = threadIdx.x;
  const int w = tid >> 6, l = tid & 63;
  const int g = l >> 4, c = l & 15;
  const int flat = blockIdx.x;
  const int n0 = (flat & 7) * 128;                 // 1 n-block per XCD (256KB B)
  const int m0 = (flat >> 3) * 128;
  const int wr = (w >> 1) * 64, wc = (w & 1) * 64;

  f32x4 acc[4][4] = {};

  const int srow = w * 32 + (l >> 2);
  const int slc  = ((l & 3) ^ ((l >> 3) & 3)) * 8;
  const unsigned short* Ag = A  + (size_t)(m0 + srow) * KD_ + slc;
  const unsigned short* Bg = Bt + (size_t)(n0 + srow) * KD_ + slc;

  const int sA = (c >> 1) & 3;

#define GSTAGE(buf, kt) do {                                    \
    gload16(Ag + (kt),            &Al[buf][(w*32)*32]);         \
    gload16(Ag + 16*KD_ + (kt),   &Al[buf][(w*32+16)*32]);      \
    gload16(Bg + (kt),            &Bl[buf][(w*32)*32]);         \
    gload16(Bg + 16*KD_ + (kt),   &Bl[buf][(w*32+16)*32]);      \
  } while (0)

  GSTAGE(0, 0);
  int cur = 0;
  for (int kt = 0; kt < KD_; kt += 32) {
    if (kt + 32 < KD_) {
      GSTAGE(cur ^ 1, kt + 32);
      asm volatile("s_waitcnt vmcnt(4)" ::: "memory");
    } else {
      asm volatile("s_waitcnt vmcnt(0)" ::: "memory");
    }
    __builtin_amdgcn_s_barrier();
    __builtin_amdgcn_sched_barrier(0);
    bf16x8 af[4], bfr[4];
#pragma unroll
    for (int i = 0; i < 4; ++i)
      af[i] = ldfrag(&Al[cur][(wr + i * 16 + c) * 32 + ((g ^ sA) << 3)]);
#pragma unroll
    for (int j = 0; j < 4; ++j)
      bfr[j] = ldfrag(&Bl[cur][(wc + j * 16 + c) * 32 + ((g ^ sA) << 3)]);
#pragma unroll
    for (int i = 0; i < 4; ++i)
#pragma unroll
      for (int j = 0; j < 4; ++j)
        acc[i][j] = __builtin_amdgcn_mfma_f32_16x16x32_bf16(af[i], bfr[j], acc[i][j], 0, 0, 0);
    __builtin_amdgcn_sched_barrier(0);
    __builtin_amdgcn_s_barrier();
    cur ^= 1;
  }
#undef GSTAGE

#pragma unroll
  for (int i = 0; i < 4; ++i)
#pragma unroll
    for (int j = 0; j < 4; ++j)
#pragma unroll
      for (int r = 0; r < 4; ++r) {
        const int m = m0 + wr + i * 16 + g * 4 + r;
        const int n = n0 + wc + j * 16 + c;
        C[(size_t)m * D_ + n] = acc[i][j][r] + bias[n];
      }
}

// ------------- causal flash attention (round-4 measured-best, unchanged) -------------
__global__ __launch_bounds__(256) void attn_fwd4(
    const unsigned short* __restrict__ Q,   // [BH][S][64] (pre-scaled by 0.18033688)
    const unsigned short* __restrict__ Kg,  // [BH][S][64]
    const unsigned short* __restrict__ Vt,  // [BH][64][S]
    unsigned short* __restrict__ O)         // [B][S][1024] bf16
{
  __shared__ unsigned short Kl[2][64 * 64];
  __shared__ unsigned short Vl[2][64 * 64];

  const int tid = threadIdx.x;
  const int w = tid >> 6, l = tid & 63;
  const int q32 = l & 31, hi = l >> 5;

  // XCD-chunked swizzle: all 8 pair-blocks of one bh land on one XCD.
  const int raw = blockIdx.y * 8 + blockIdx.x;         // 0..511
  const int work = (raw & 7) * 64 + (raw >> 3);
  const int bh = work >> 3;
  const int p  = work & 7;
  const int q0A = p * 128;
  const int q0B = (15 - p) * 128;
  const int nA = 2 * (p + 1);
  const int nB = 2 * (16 - p);
  const int total = nA + nB;                           // 34 always

  const unsigned short* Kbh = Kg + (size_t)bh * (S_ * HD_);
  const unsigned short* Vbh = Vt + (size_t)bh * (HD_ * S_);

  bf16x8 qf[4];
  auto loadQ = [&](int q0) {
    const unsigned short* Qrow = Q + ((size_t)bh * S_ + q0 + w * 32 + q32) * HD_ + hi * 8;
#pragma unroll
    for (int s = 0; s < 4; ++s) qf[s] = ldfrag(Qrow + s * 16);
  };

  f32x16 od0 = {}, od1 = {};
  float lrun = 0.f;

  const int krow = w * 16 + (l >> 3);
  const int slc = ((l & 7) ^ (l >> 3)) * 8;  // inverse-swizzled source chunk

#define LDSOFF(r, ch) ((r) * 64 + (((ch) ^ ((r) & 7)) << 3))

#define STAGE(buf, tile) do {                                                   \
    const int k0s = (tile) * 64;                                                \
    gload16(Kbh + (size_t)(k0s + krow) * HD_ + slc,     &Kl[buf][(w*16)*64]);   \
    gload16(Kbh + (size_t)(k0s + krow + 8) * HD_ + slc, &Kl[buf][(w*16+8)*64]); \
    gload16(Vbh + (size_t)krow * S_ + k0s + slc,        &Vl[buf][(w*16)*64]);   \
    gload16(Vbh + (size_t)(krow + 8) * S_ + k0s + slc,  &Vl[buf][(w*16+8)*64]); \
  } while (0)

  auto epilogue = [&](int q0) {
    const float rl = 1.0f / lrun;
    const int bb = bh >> 4, hh = bh & 15;
    const int sq = q0 + w * 32 + q32;
    unsigned short* Orow = O + ((size_t)bb * S_ + sq) * D_ + hh * HD_;
#pragma unroll
    for (int rr = 0; rr < 4; ++rr) {
      uint2 v0, v1;
      v0.x = cvtpk(od0[4 * rr] * rl,     od0[4 * rr + 1] * rl);
      v0.y = cvtpk(od0[4 * rr + 2] * rl, od0[4 * rr + 3] * rl);
      *reinterpret_cast<uint2*>(Orow + 8 * rr + 4 * hi) = v0;
      v1.x = cvtpk(od1[4 * rr] * rl,     od1[4 * rr + 1] * rl);
      v1.y = cvtpk(od1[4 * rr + 2] * rl, od1[4 * rr + 3] * rl);
      *reinterpret_cast<uint2*>(Orow + 32 + 8 * rr + 4 * hi) = v1;
    }
  };

  loadQ(q0A);
  STAGE(0, 0);
  int cur = 0;
  int q0 = q0A;

  for (int idx = 0; idx < total; ++idx) {
    const bool inA = idx < nA;
    const int kv = inA ? idx : idx - nA;
    const int k0 = kv * 64;
    if (idx + 1 < total) {
      const int nkv = (idx + 1 < nA) ? idx + 1 : idx + 1 - nA;
      STAGE(cur ^ 1, nkv);
      asm volatile("s_waitcnt vmcnt(4)" ::: "memory");
    } else {
      asm volatile("s_waitcnt vmcnt(0)" ::: "memory");
    }
    __builtin_amdgcn_s_barrier();
    __builtin_amdgcn_sched_barrier(0);

    const int wqmin = q0 + w * 32;
    if (k0 <= wqmin + 31) {   // wave-tile not fully masked
      const bool live1 = (k0 + 32 <= wqmin + 31);
      const unsigned short* Kb_ = &Kl[cur][0];
      const unsigned short* Vb_ = &Vl[cur][0];

      // ---- S^T = K x Q^T ----
      f32x16 st0 = {}, st1 = {};
      __builtin_amdgcn_s_setprio(1);
#pragma unroll
      for (int s = 0; s < 4; ++s) {
        bf16x8 kf = ldfrag(Kb_ + LDSOFF(q32, 2 * s + hi));
        st0 = __builtin_amdgcn_mfma_f32_32x32x16_bf16(kf, qf[s], st0, 0, 0, 0);
      }
      if (live1) {
#pragma unroll
        for (int s = 0; s < 4; ++s) {
          bf16x8 kf = ldfrag(Kb_ + LDSOFF(32 + q32, 2 * s + hi));
          st1 = __builtin_amdgcn_mfma_f32_32x32x16_bf16(kf, qf[s], st1, 0, 0, 0);
        }
      }
      __builtin_amdgcn_s_setprio(0);

      // ---- causal mask (diagonal region only) ----
      if (k0 + 63 > wqmin) {
        const int rel = wqmin + q32 - k0;
#pragma unroll
        for (int r = 0; r < 16; ++r) {
          const int kva = (r & 3) + 8 * (r >> 2) + 4 * hi;
          if (kva > rel) st0[r] = -1e30f;
        }
        if (live1) {
#pragma unroll
          for (int r = 0; r < 16; ++r) {
            const int kva = (r & 3) + 8 * (r >> 2) + 4 * hi;
            if (kva + 32 > rel) st1[r] = -1e30f;
          }
        }
      }

      // ---- p = exp2(st) directly; row-sum via packed f32 adds ----
      float2 e0[8], e1[8];
#pragma unroll
      for (int r = 0; r < 8; ++r) {
        e0[r].x = __builtin_amdgcn_exp2f(st0[2 * r]);
        e0[r].y = __builtin_amdgcn_exp2f(st0[2 * r + 1]);
      }
      float2 a0 = pkadd2(pkadd2(e0[0], e0[1]), pkadd2(e0[2], e0[3]));
      float2 a1 = pkadd2(pkadd2(e0[4], e0[5]), pkadd2(e0[6], e0[7]));
      float2 asum = pkadd2(a0, a1);
      if (live1) {
#pragma unroll
        for (int r = 0; r < 8; ++r) {
          e1[r].x = __builtin_amdgcn_exp2f(st1[2 * r]);
          e1[r].y = __builtin_amdgcn_exp2f(st1[2 * r + 1]);
        }
        float2 b0 = pkadd2(pkadd2(e1[0], e1[1]), pkadd2(e1[2], e1[3]));
        float2 b1 = pkadd2(pkadd2(e1[4], e1[5]), pkadd2(e1[6], e1[7]));
        asum = pkadd2(asum, pkadd2(b0, b1));
      }
      float ps = asum.x + asum.y;
      ps += __shfl_xor(ps, 32);
      lrun += ps;

      // ---- P -> bf16 A-frags via cvt_pk + permlane32_swap ----
      unsigned int W0, W1, W2, W3, W4, W5, W6, W7;
      W0 = cvtpk(e0[0].x, e0[0].y); W1 = cvtpk(e0[1].x, e0[1].y);
      W2 = cvtpk(e0[2].x, e0[2].y); W3 = cvtpk(e0[3].x, e0[3].y);
      W4 = cvtpk(e0[4].x, e0[4].y); W5 = cvtpk(e0[5].x, e0[5].y);
      W6 = cvtpk(e0[6].x, e0[6].y); W7 = cvtpk(e0[7].x, e0[7].y);
      plswap(W0, W2); plswap(W1, W3); plswap(W4, W6); plswap(W5, W7);
      const bf16x8 pa0 = mkfrag(W0, W1, W2, W3);
      const bf16x8 pa1 = mkfrag(W4, W5, W6, W7);
      bf16x8 pa2, pa3;
      if (live1) {
        W0 = cvtpk(e1[0].x, e1[0].y); W1 = cvtpk(e1[1].x, e1[1].y);
        W2 = cvtpk(e1[2].x, e1[2].y); W3 = cvtpk(e1[3].x, e1[3].y);
        W4 = cvtpk(e1[4].x, e1[4].y); W5 = cvtpk(e1[5].x, e1[5].y);
        W6 = cvtpk(e1[6].x, e1[6].y); W7 = cvtpk(e1[7].x, e1[7].y);
        plswap(W0, W2); plswap(W1, W3); plswap(W4, W6); plswap(W5, W7);
        pa2 = mkfrag(W0, W1, W2, W3);
        pa3 = mkfrag(W4, W5, W6, W7);
      }

      // ---- O^T += V^T x P^T ----
      __builtin_amdgcn_s_setprio(1);
#pragma unroll
      for (int s = 0; s < 2; ++s) {
        const bf16x8 pa = (s == 0) ? pa0 : pa1;
        bf16x8 vf = ldfrag(Vb_ + LDSOFF(q32, 2 * s + hi));
        od0 = __builtin_amdgcn_mfma_f32_32x32x16_bf16(vf, pa, od0, 0, 0, 0);
        bf16x8 vg = ldfrag(Vb_ + LDSOFF(32 + q32, 2 * s + hi));
        od1 = __builtin_amdgcn_mfma_f32_32x32x16_bf16(vg, pa, od1, 0, 0, 0);
      }
      if (live1) {
#pragma unroll
        for (int s = 2; s < 4; ++s) {
          const bf16x8 pa = (s == 2) ? pa2 : pa3;
          bf16x8 vf = ldfrag(Vb_ + LDSOFF(q32, 2 * s + hi));
          od0 = __builtin_amdgcn_mfma_f32_32x32x16_bf16(vf, pa, od0, 0, 0, 0);
          bf16x8 vg = ldfrag(Vb_ + LDSOFF(32 + q32, 2 * s + hi));
          od1 = __builtin_amdgcn_mfma_f32_32x32x16_bf16(vg, pa, od1, 0, 0, 0);
        }
      }
      __builtin_amdgcn_s_setprio(0);
    }

    __builtin_amdgcn_sched_barrier(0);
    __builtin_amdgcn_s_barrier();

    // transition A -> B (register-only; no LDS hazard)
    if (idx == nA - 1) {
      epilogue(q0A);
      loadQ(q0B);
      od0 = {}; od1 = {};
      lrun = 0.f;
      q0 = q0B;
    }
    cur ^= 1;
  }

  epilogue(q0B);
#undef STAGE
#undef LDSOFF
}

extern "C" void kernel_launch(void* const* d_in, const int* in_sizes, int n_in,
                              void* d_out, int out_size, void* d_ws, size_t ws_size,
                              hipStream_t stream) {
  (void)in_sizes; (void)n_in; (void)out_size; (void)ws_size;
  const float* x     = (const float*)d_in[0];
  const float* w_in  = (const float*)d_in[1];
  const float* b_in  = (const float*)d_in[2];
  const float* w_out = (const float*)d_in[3];
  const float* b_out = (const float*)d_in[4];
  float* out = (float*)d_out;
  char* ws = (char*)d_ws;
  const size_t MB = 1024 * 1024;
  unsigned short* xb     = (unsigned short*)(ws);             // 16MB
  unsigned short* w_inb  = (unsigned short*)(ws + 16 * MB);   // 6MB
  unsigned short* w_outb = (unsigned short*)(ws + 22 * MB);   // 2MB
  unsigned short* Qb     = (unsigned short*)(ws + 24 * MB);   // 16MB
  unsigned short* Kb     = (unsigned short*)(ws + 40 * MB);   // 16MB
  unsigned short* Vt     = (unsigned short*)(ws + 56 * MB);   // 16MB (transposed V)
  unsigned short* Ob     = (unsigned short*)(ws + 72 * MB);   // 16MB

  prep<<<8192, 256, 0, stream>>>(x, xb, w_in, w_inb, w_out, w_outb);
  qkv_gemm<<<1536, 256, 0, stream>>>(xb, w_inb, b_in, Qb, Kb, Vt);
  attn_fwd4<<<dim3(8, 64), 256, 0, stream>>>(Qb, Kb, Vt, Ob);
  out_gemm<<<512, 256, 0, stream>>>(Ob, w_outb, b_out, out);
}

// Round 10
// 167.923 us; speedup vs baseline: 1.1087x; 1.0439x over previous
//
#include <hip/hip_runtime.h>
#include <stdint.h>

// Problem constants
#define B_   4
#define S_   2048
#define D_   1024
#define H_   16
#define HD_  64
#define BH_  (B_*H_)      // 64
#define M_   (B_*S_)      // 8192
#define KD_  1024         // GEMM K (= D)

typedef __bf16 bf16x8 __attribute__((ext_vector_type(8)));
typedef float f32x4 __attribute__((ext_vector_type(4)));
typedef float f32x16 __attribute__((ext_vector_type(16)));
typedef unsigned int u32x4 __attribute__((ext_vector_type(4)));

__device__ __forceinline__ unsigned short f2bf(float f) {
  unsigned int u = __float_as_uint(f);
  u = u + 0x7fffu + ((u >> 16) & 1u);   // RNE
  return (unsigned short)(u >> 16);
}

__device__ __forceinline__ void gload16(const void* g, void* lds) {
  __builtin_amdgcn_global_load_lds(
      (__attribute__((address_space(1))) void*)(g),
      (__attribute__((address_space(3))) void*)(lds),
      16, 0, 0);
}

__device__ __forceinline__ bf16x8 ldfrag(const unsigned short* p) {
  return *reinterpret_cast<const bf16x8*>(p);
}

__device__ __forceinline__ unsigned int cvtpk(float lo, float hi) {
  unsigned int r;
  asm("v_cvt_pk_bf16_f32 %0, %1, %2" : "=v"(r) : "v"(lo), "v"(hi));
  return r;
}

// v_permlane32_swap_b32: a's upper 32 lanes <-> b's lower 32 lanes.
__device__ __forceinline__ void plswap(unsigned int& a, unsigned int& b) {
  asm("v_permlane32_swap_b32 %0, %1" : "+v"(a), "+v"(b));
}

__device__ __forceinline__ float2 pkadd2(float2 a, float2 b) {
  float2 r;
  asm("v_pk_add_f32 %0, %1, %2" : "=v"(r) : "v"(a), "v"(b));
  return r;
}

__device__ __forceinline__ bf16x8 mkfrag(unsigned int a, unsigned int b,
                                         unsigned int c, unsigned int d) {
  union { unsigned int w[4]; bf16x8 v; } u;
  u.w[0] = a; u.w[1] = b; u.w[2] = c; u.w[3] = d;
  return u.v;
}

// ------------- fused prep: x f32->bf16 copy + both weight transposes -------------
// blocks [0,4096): xconv; [4096,7168): w_in^T; [7168,8192): w_out^T.
__global__ __launch_bounds__(256) void prep(
    const float* __restrict__ x,     unsigned short* __restrict__ xb,
    const float* __restrict__ w_in,  unsigned short* __restrict__ w_inb,
    const float* __restrict__ w_out, unsigned short* __restrict__ w_outb) {
  const int bid = blockIdx.x;
  const int tid = threadIdx.x;
  if (bid < 4096) {
    const size_t i = (size_t)bid * 256 + tid;
    const float4* p = reinterpret_cast<const float4*>(x) + i * 2;
    float4 a = p[0], b = p[1];
    union { u32x4 v; unsigned short u[8]; } cv;
    cv.u[0] = f2bf(a.x); cv.u[1] = f2bf(a.y); cv.u[2] = f2bf(a.z); cv.u[3] = f2bf(a.w);
    cv.u[4] = f2bf(b.x); cv.u[5] = f2bf(b.y); cv.u[6] = f2bf(b.z); cv.u[7] = f2bf(b.w);
    *reinterpret_cast<u32x4*>(xb + i * 8) = cv.v;
    return;
  }
  __shared__ float t[32][33];
  const float* src; unsigned short* dst; int R, C, c0, r0;
  if (bid < 7168) {
    const int b = bid - 4096;                 // w_in: R=1024, C=3072, grid 96x32
    src = w_in; dst = w_inb; R = 1024; C = 3072;
    c0 = (b % 96) * 32; r0 = (b / 96) * 32;
  } else {
    const int b = bid - 7168;                 // w_out: R=1024, C=1024, grid 32x32
    src = w_out; dst = w_outb; R = 1024; C = 1024;
    c0 = (b % 32) * 32; r0 = (b / 32) * 32;
  }
  const int xx = tid & 31, yy = tid >> 5;
#pragma unroll
  for (int y2 = yy; y2 < 32; y2 += 8)
    t[y2][xx] = src[(size_t)(r0 + y2) * C + c0 + xx];
  __syncthreads();
#pragma unroll
  for (int y2 = yy; y2 < 32; y2 += 8)
    dst[(size_t)(c0 + y2) * R + r0 + xx] = f2bf(t[xx][y2]);
}

// ------------- QKV GEMM (round-4 measured-best: 2-buf, vmcnt(4), m-panel grid) -------------
__global__ __launch_bounds__(256) void qkv_gemm(
    const unsigned short* __restrict__ A,    // [8192][1024] bf16 (x)
    const unsigned short* __restrict__ Bt,   // [3072][1024] bf16 (w_in^T)
    const float* __restrict__ bias,          // [3072]
    unsigned short* __restrict__ Qo,         // [BH][S][64], pre-scaled
    unsigned short* __restrict__ Ko,         // [BH][S][64]
    unsigned short* __restrict__ Vto)        // [BH][64][S]  (transposed)
{
  __shared__ unsigned short Al[2][128 * 32];
  __shared__ unsigned short Bl[2][128 * 32];
  const int tid = threadIdx.x;
  const int w = tid >> 6, l = tid & 63;
  const int g = l >> 4, c = l & 15;
  const int m0 = blockIdx.y * 128, n0 = blockIdx.x * 128;
  const int wr = (w >> 1) * 64, wc = (w & 1) * 64;

  f32x4 acc[4][4] = {};

  const int srow = w * 32 + (l >> 2);
  const int slc  = ((l & 3) ^ ((l >> 3) & 3)) * 8;
  const unsigned short* Ag = A  + (size_t)(m0 + srow) * KD_ + slc;
  const unsigned short* Bg = Bt + (size_t)(n0 + srow) * KD_ + slc;

  const int sA = (c >> 1) & 3;

#define GSTAGE(buf, kt) do {                                    \
    gload16(Ag + (kt),            &Al[buf][(w*32)*32]);         \
    gload16(Ag + 16*KD_ + (kt),   &Al[buf][(w*32+16)*32]);      \
    gload16(Bg + (kt),            &Bl[buf][(w*32)*32]);         \
    gload16(Bg + 16*KD_ + (kt),   &Bl[buf][(w*32+16)*32]);      \
  } while (0)

  GSTAGE(0, 0);
  int cur = 0;
  for (int kt = 0; kt < KD_; kt += 32) {
    if (kt + 32 < KD_) {
      GSTAGE(cur ^ 1, kt + 32);
      asm volatile("s_waitcnt vmcnt(4)" ::: "memory");
    } else {
      asm volatile("s_waitcnt vmcnt(0)" ::: "memory");
    }
    __builtin_amdgcn_s_barrier();
    __builtin_amdgcn_sched_barrier(0);
    bf16x8 af[4], bfr[4];
#pragma unroll
    for (int i = 0; i < 4; ++i)
      af[i] = ldfrag(&Al[cur][(wr + i * 16 + c) * 32 + ((g ^ sA) << 3)]);
#pragma unroll
    for (int j = 0; j < 4; ++j)
      bfr[j] = ldfrag(&Bl[cur][(wc + j * 16 + c) * 32 + ((g ^ sA) << 3)]);
#pragma unroll
    for (int i = 0; i < 4; ++i)
#pragma unroll
      for (int j = 0; j < 4; ++j)
        acc[i][j] = __builtin_amdgcn_mfma_f32_16x16x32_bf16(af[i], bfr[j], acc[i][j], 0, 0, 0);
    __builtin_amdgcn_sched_barrier(0);
    __builtin_amdgcn_s_barrier();
    cur ^= 1;
  }
#undef GSTAGE

  if (n0 >= 2048) {
    // V: write directly transposed (4 consecutive tokens -> one 8B packed store).
#pragma unroll
    for (int i = 0; i < 4; ++i)
#pragma unroll
      for (int j = 0; j < 4; ++j) {
        const int ng = n0 + wc + j * 16 + c;
        const int n  = ng - 2048;
        const int hh = n >> 6, dim = n & 63;
        const int m  = m0 + wr + i * 16 + g * 4;
        const int bb = m >> 11, ss = m & 2047;
        const float bv = bias[ng];
        uint2 pk;
        pk.x = cvtpk(acc[i][j][0] + bv, acc[i][j][1] + bv);
        pk.y = cvtpk(acc[i][j][2] + bv, acc[i][j][3] + bv);
        *reinterpret_cast<uint2*>(
            &Vto[((size_t)(bb * H_ + hh) * HD_ + dim) * S_ + ss]) = pk;
      }
  } else {
#pragma unroll
    for (int i = 0; i < 4; ++i)
#pragma unroll
      for (int j = 0; j < 4; ++j)
#pragma unroll
        for (int r = 0; r < 4; ++r) {
          const int m = m0 + wr + i * 16 + g * 4 + r;
          const int n = n0 + wc + j * 16 + c;
          float v = acc[i][j][r] + bias[n];
          const int which = n >> 10;
          const int dp = n & 1023;
          const int hh = dp >> 6, dim = dp & 63;
          const int bb = m >> 11, ss = m & 2047;
          const size_t idx = ((size_t)(bb * H_ + hh) * S_ + ss) * HD_ + dim;
          // Q scale: 1/sqrt(hd) * log2(e)  (softmax runs in exp2 domain)
          if (which == 0) Qo[idx] = f2bf(v * 0.18033688f);
          else            Ko[idx] = f2bf(v);
        }
  }
}

// ------------- out GEMM (round-4 measured-best) -------------
__global__ __launch_bounds__(256) void out_gemm(
    const unsigned short* __restrict__ A,
    const unsigned short* __restrict__ Bt,
    const float* __restrict__ bias,
    float* __restrict__ C)
{
  __shared__ unsigned short Al[2][128 * 32];
  __shared__ unsigned short Bl[2][128 * 32];
  const int tid = threadIdx.x;
  const int w = tid >> 6, l = tid & 63;
  const int g = l >> 4, c = l & 15;
  const int m0 = blockIdx.y * 128, n0 = blockIdx.x * 128;
  const int wr = (w >> 1) * 64, wc = (w & 1) * 64;

  f32x4 acc[4][4] = {};

  const int srow = w * 32 + (l >> 2);
  const int slc  = ((l & 3) ^ ((l >> 3) & 3)) * 8;
  const unsigned short* Ag = A  + (size_t)(m0 + srow) * KD_ + slc;
  const unsigned short* Bg = Bt + (size_t)(n0 + srow) * KD_ + slc;

  const int sA = (c >> 1) & 3;

#define GSTAGE(buf, kt) do {                                    \
    gload16(Ag + (kt),            &Al[buf][(w*32)*32]);         \
    gload16(Ag + 16*KD_ + (kt),   &Al[buf][(w*32+16)*32]);      \
    gload16(Bg + (kt),            &Bl[buf][(w*32)*32]);         \
    gload16(Bg + 16*KD_ + (kt),   &Bl[buf][(w*32+16)*32]);      \
  } while (0)

  GSTAGE(0, 0);
  int cur = 0;
  for (int kt = 0; kt < KD_; kt += 32) {
    if (kt + 32 < KD_) {
      GSTAGE(cur ^ 1, kt + 32);
      asm volatile("s_waitcnt vmcnt(4)" ::: "memory");
    } else {
      asm volatile("s_waitcnt vmcnt(0)" ::: "memory");
    }
    __builtin_amdgcn_s_barrier();
    __builtin_amdgcn_sched_barrier(0);
    bf16x8 af[4], bfr[4];
#pragma unroll
    for (int i = 0; i < 4; ++i)
      af[i] = ldfrag(&Al[cur][(wr + i * 16 + c) * 32 + ((g ^ sA) << 3)]);
#pragma unroll
    for (int j = 0; j < 4; ++j)
      bfr[j] = ldfrag(&Bl[cur][(wc + j * 16 + c) * 32 + ((g ^ sA) << 3)]);
#pragma unroll
    for (int i = 0; i < 4; ++i)
#pragma unroll
      for (int j = 0; j < 4; ++j)
        acc[i][j] = __builtin_amdgcn_mfma_f32_16x16x32_bf16(af[i], bfr[j], acc[i][j], 0, 0, 0);
    __builtin_amdgcn_sched_barrier(0);
    __builtin_amdgcn_s_barrier();
    cur ^= 1;
  }
#undef GSTAGE

#pragma unroll
  for (int i = 0; i < 4; ++i)
#pragma unroll
    for (int j = 0; j < 4; ++j)
#pragma unroll
      for (int r = 0; r < 4; ++r) {
        const int m = m0 + wr + i * 16 + g * 4 + r;
        const int n = n0 + wc + j * 16 + c;
        C[(size_t)m * D_ + n] = acc[i][j][r] + bias[n];
      }
}

// ------------- causal flash attention (round-4 measured-best, unchanged) -------------
__global__ __launch_bounds__(256) void attn_fwd4(
    const unsigned short* __restrict__ Q,   // [BH][S][64] (pre-scaled by 0.18033688)
    const unsigned short* __restrict__ Kg,  // [BH][S][64]
    const unsigned short* __restrict__ Vt,  // [BH][64][S]
    unsigned short* __restrict__ O)         // [B][S][1024] bf16
{
  __shared__ unsigned short Kl[2][64 * 64];
  __shared__ unsigned short Vl[2][64 * 64];

  const int tid = threadIdx.x;
  const int w = tid >> 6, l = tid & 63;
  const int q32 = l & 31, hi = l >> 5;

  // XCD-chunked swizzle: all 8 pair-blocks of one bh land on one XCD.
  const int raw = blockIdx.y * 8 + blockIdx.x;         // 0..511
  const int work = (raw & 7) * 64 + (raw >> 3);
  const int bh = work >> 3;
  const int p  = work & 7;
  const int q0A = p * 128;
  const int q0B = (15 - p) * 128;
  const int nA = 2 * (p + 1);
  const int nB = 2 * (16 - p);
  const int total = nA + nB;                           // 34 always

  const unsigned short* Kbh = Kg + (size_t)bh * (S_ * HD_);
  const unsigned short* Vbh = Vt + (size_t)bh * (HD_ * S_);

  bf16x8 qf[4];
  auto loadQ = [&](int q0) {
    const unsigned short* Qrow = Q + ((size_t)bh * S_ + q0 + w * 32 + q32) * HD_ + hi * 8;
#pragma unroll
    for (int s = 0; s < 4; ++s) qf[s] = ldfrag(Qrow + s * 16);
  };

  f32x16 od0 = {}, od1 = {};
  float lrun = 0.f;

  const int krow = w * 16 + (l >> 3);
  const int slc = ((l & 7) ^ (l >> 3)) * 8;  // inverse-swizzled source chunk

#define LDSOFF(r, ch) ((r) * 64 + (((ch) ^ ((r) & 7)) << 3))

#define STAGE(buf, tile) do {                                                   \
    const int k0s = (tile) * 64;                                                \
    gload16(Kbh + (size_t)(k0s + krow) * HD_ + slc,     &Kl[buf][(w*16)*64]);   \
    gload16(Kbh + (size_t)(k0s + krow + 8) * HD_ + slc, &Kl[buf][(w*16+8)*64]); \
    gload16(Vbh + (size_t)krow * S_ + k0s + slc,        &Vl[buf][(w*16)*64]);   \
    gload16(Vbh + (size_t)(krow + 8) * S_ + k0s + slc,  &Vl[buf][(w*16+8)*64]); \
  } while (0)

  auto epilogue = [&](int q0) {
    const float rl = 1.0f / lrun;
    const int bb = bh >> 4, hh = bh & 15;
    const int sq = q0 + w * 32 + q32;
    unsigned short* Orow = O + ((size_t)bb * S_ + sq) * D_ + hh * HD_;
#pragma unroll
    for (int rr = 0; rr < 4; ++rr) {
      uint2 v0, v1;
      v0.x = cvtpk(od0[4 * rr] * rl,     od0[4 * rr + 1] * rl);
      v0.y = cvtpk(od0[4 * rr + 2] * rl, od0[4 * rr + 3] * rl);
      *reinterpret_cast<uint2*>(Orow + 8 * rr + 4 * hi) = v0;
      v1.x = cvtpk(od1[4 * rr] * rl,     od1[4 * rr + 1] * rl);
      v1.y = cvtpk(od1[4 * rr + 2] * rl, od1[4 * rr + 3] * rl);
      *reinterpret_cast<uint2*>(Orow + 32 + 8 * rr + 4 * hi) = v1;
    }
  };

  loadQ(q0A);
  STAGE(0, 0);
  int cur = 0;
  int q0 = q0A;

  for (int idx = 0; idx < total; ++idx) {
    const bool inA = idx < nA;
    const int kv = inA ? idx : idx - nA;
    const int k0 = kv * 64;
    if (idx + 1 < total) {
      const int nkv = (idx + 1 < nA) ? idx + 1 : idx + 1 - nA;
      STAGE(cur ^ 1, nkv);
      asm volatile("s_waitcnt vmcnt(4)" ::: "memory");
    } else {
      asm volatile("s_waitcnt vmcnt(0)" ::: "memory");
    }
    __builtin_amdgcn_s_barrier();
    __builtin_amdgcn_sched_barrier(0);

    const int wqmin = q0 + w * 32;
    if (k0 <= wqmin + 31) {   // wave-tile not fully masked
      const bool live1 = (k0 + 32 <= wqmin + 31);
      const unsigned short* Kb_ = &Kl[cur][0];
      const unsigned short* Vb_ = &Vl[cur][0];

      // ---- S^T = K x Q^T ----
      f32x16 st0 = {}, st1 = {};
      __builtin_amdgcn_s_setprio(1);
#pragma unroll
      for (int s = 0; s < 4; ++s) {
        bf16x8 kf = ldfrag(Kb_ + LDSOFF(q32, 2 * s + hi));
        st0 = __builtin_amdgcn_mfma_f32_32x32x16_bf16(kf, qf[s], st0, 0, 0, 0);
      }
      if (live1) {
#pragma unroll
        for (int s = 0; s < 4; ++s) {
          bf16x8 kf = ldfrag(Kb_ + LDSOFF(32 + q32, 2 * s + hi));
          st1 = __builtin_amdgcn_mfma_f32_32x32x16_bf16(kf, qf[s], st1, 0, 0, 0);
        }
      }
      __builtin_amdgcn_s_setprio(0);

      // ---- causal mask (diagonal region only) ----
      if (k0 + 63 > wqmin) {
        const int rel = wqmin + q32 - k0;
#pragma unroll
        for (int r = 0; r < 16; ++r) {
          const int kva = (r & 3) + 8 * (r >> 2) + 4 * hi;
          if (kva > rel) st0[r] = -1e30f;
        }
        if (live1) {
#pragma unroll
          for (int r = 0; r < 16; ++r) {
            const int kva = (r & 3) + 8 * (r >> 2) + 4 * hi;
            if (kva + 32 > rel) st1[r] = -1e30f;
          }
        }
      }

      // ---- p = exp2(st) directly; row-sum via packed f32 adds ----
      float2 e0[8], e1[8];
#pragma unroll
      for (int r = 0; r < 8; ++r) {
        e0[r].x = __builtin_amdgcn_exp2f(st0[2 * r]);
        e0[r].y = __builtin_amdgcn_exp2f(st0[2 * r + 1]);
      }
      float2 a0 = pkadd2(pkadd2(e0[0], e0[1]), pkadd2(e0[2], e0[3]));
      float2 a1 = pkadd2(pkadd2(e0[4], e0[5]), pkadd2(e0[6], e0[7]));
      float2 asum = pkadd2(a0, a1);
      if (live1) {
#pragma unroll
        for (int r = 0; r < 8; ++r) {
          e1[r].x = __builtin_amdgcn_exp2f(st1[2 * r]);
          e1[r].y = __builtin_amdgcn_exp2f(st1[2 * r + 1]);
        }
        float2 b0 = pkadd2(pkadd2(e1[0], e1[1]), pkadd2(e1[2], e1[3]));
        float2 b1 = pkadd2(pkadd2(e1[4], e1[5]), pkadd2(e1[6], e1[7]));
        asum = pkadd2(asum, pkadd2(b0, b1));
      }
      float ps = asum.x + asum.y;
      ps += __shfl_xor(ps, 32);
      lrun += ps;

      // ---- P -> bf16 A-frags via cvt_pk + permlane32_swap ----
      unsigned int W0, W1, W2, W3, W4, W5, W6, W7;
      W0 = cvtpk(e0[0].x, e0[0].y); W1 = cvtpk(e0[1].x, e0[1].y);
      W2 = cvtpk(e0[2].x, e0[2].y); W3 = cvtpk(e0[3].x, e0[3].y);
      W4 = cvtpk(e0[4].x, e0[4].y); W5 = cvtpk(e0[5].x, e0[5].y);
      W6 = cvtpk(e0[6].x, e0[6].y); W7 = cvtpk(e0[7].x, e0[7].y);
      plswap(W0, W2); plswap(W1, W3); plswap(W4, W6); plswap(W5, W7);
      const bf16x8 pa0 = mkfrag(W0, W1, W2, W3);
      const bf16x8 pa1 = mkfrag(W4, W5, W6, W7);
      bf16x8 pa2, pa3;
      if (live1) {
        W0 = cvtpk(e1[0].x, e1[0].y); W1 = cvtpk(e1[1].x, e1[1].y);
        W2 = cvtpk(e1[2].x, e1[2].y); W3 = cvtpk(e1[3].x, e1[3].y);
        W4 = cvtpk(e1[4].x, e1[4].y); W5 = cvtpk(e1[5].x, e1[5].y);
        W6 = cvtpk(e1[6].x, e1[6].y); W7 = cvtpk(e1[7].x, e1[7].y);
        plswap(W0, W2); plswap(W1, W3); plswap(W4, W6); plswap(W5, W7);
        pa2 = mkfrag(W0, W1, W2, W3);
        pa3 = mkfrag(W4, W5, W6, W7);
      }

      // ---- O^T += V^T x P^T ----
      __builtin_amdgcn_s_setprio(1);
#pragma unroll
      for (int s = 0; s < 2; ++s) {
        const bf16x8 pa = (s == 0) ? pa0 : pa1;
        bf16x8 vf = ldfrag(Vb_ + LDSOFF(q32, 2 * s + hi));
        od0 = __builtin_amdgcn_mfma_f32_32x32x16_bf16(vf, pa, od0, 0, 0, 0);
        bf16x8 vg = ldfrag(Vb_ + LDSOFF(32 + q32, 2 * s + hi));
        od1 = __builtin_amdgcn_mfma_f32_32x32x16_bf16(vg, pa, od1, 0, 0, 0);
      }
      if (live1) {
#pragma unroll
        for (int s = 2; s < 4; ++s) {
          const bf16x8 pa = (s == 2) ? pa2 : pa3;
          bf16x8 vf = ldfrag(Vb_ + LDSOFF(q32, 2 * s + hi));
          od0 = __builtin_amdgcn_mfma_f32_32x32x16_bf16(vf, pa, od0, 0, 0, 0);
          bf16x8 vg = ldfrag(Vb_ + LDSOFF(32 + q32, 2 * s + hi));
          od1 = __builtin_amdgcn_mfma_f32_32x32x16_bf16(vg, pa, od1, 0, 0, 0);
        }
      }
      __builtin_amdgcn_s_setprio(0);
    }

    __builtin_amdgcn_sched_barrier(0);
    __builtin_amdgcn_s_barrier();

    // transition A -> B (register-only; no LDS hazard)
    if (idx == nA - 1) {
      epilogue(q0A);
      loadQ(q0B);
      od0 = {}; od1 = {};
      lrun = 0.f;
      q0 = q0B;
    }
    cur ^= 1;
  }

  epilogue(q0B);
#undef STAGE
#undef LDSOFF
}

extern "C" void kernel_launch(void* const* d_in, const int* in_sizes, int n_in,
                              void* d_out, int out_size, void* d_ws, size_t ws_size,
                              hipStream_t stream) {
  (void)in_sizes; (void)n_in; (void)out_size; (void)ws_size;
  const float* x     = (const float*)d_in[0];
  const float* w_in  = (const float*)d_in[1];
  const float* b_in  = (const float*)d_in[2];
  const float* w_out = (const float*)d_in[3];
  const float* b_out = (const float*)d_in[4];
  float* out = (float*)d_out;
  char* ws = (char*)d_ws;
  const size_t MB = 1024 * 1024;
  unsigned short* xb     = (unsigned short*)(ws);             // 16MB
  unsigned short* w_inb  = (unsigned short*)(ws + 16 * MB);   // 6MB
  unsigned short* w_outb = (unsigned short*)(ws + 22 * MB);   // 2MB
  unsigned short* Qb     = (unsigned short*)(ws + 24 * MB);   // 16MB
  unsigned short* Kb     = (unsigned short*)(ws + 40 * MB);   // 16MB
  unsigned short* Vt     = (unsigned short*)(ws + 56 * MB);   // 16MB (transposed V)
  unsigned short* Ob     = (unsigned short*)(ws + 72 * MB);   // 16MB

  prep<<<8192, 256, 0, stream>>>(x, xb, w_in, w_inb, w_out, w_outb);
  qkv_gemm<<<dim3(24, 64), 256, 0, stream>>>(xb, w_inb, b_in, Qb, Kb, Vt);
  attn_fwd4<<<dim3(8, 64), 256, 0, stream>>>(Qb, Kb, Vt, Ob);
  out_gemm<<<dim3(8, 64), 256, 0, stream>>>(Ob, w_outb, b_out, out);
}